// Round 5
// baseline (668.848 us; speedup 1.0000x reference)
//
#include <hip/hip_runtime.h>
#include <hip/hip_bf16.h>
#include <math.h>

// Problem constants (MambaAgent reference)
#define B_   16
#define L_   1024
#define DM   512          // D_MODEL
#define DI   1024         // D_INNER
#define NST  16           // D_STATE
#define DTR  32           // DT_RANK
#define ML   (B_*L_)      // 16384 rows

typedef __hip_bfloat16 bf16;
typedef __attribute__((ext_vector_type(8))) short short8;
typedef __attribute__((ext_vector_type(4))) float f32x4;

__device__ __forceinline__ float bf2f(unsigned short u) {
  union { unsigned int i; float f; } v; v.i = ((unsigned int)u) << 16; return v.f;
}
__device__ __forceinline__ unsigned short f2bfbits(float f) {
  bf16 h = __float2bfloat16(f);
  return *(unsigned short*)&h;
}
__device__ __forceinline__ float sigmoidf_(float v) { return 1.f/(1.f+__expf(-v)); }

// ---- dtype-polymorphic scalar loads ----
template<typename T> struct WT;
template<> struct WT<bf16> {
  static __device__ __forceinline__ float ld(const void* p, size_t i) {
    return bf2f(((const unsigned short*)p)[i]);
  }
  static __device__ __forceinline__ void ld4(const void* p, size_t i, float* d) {
    const ushort4 v = *(const ushort4*)((const unsigned short*)p + i);
    d[0]=bf2f(v.x); d[1]=bf2f(v.y); d[2]=bf2f(v.z); d[3]=bf2f(v.w);
  }
};
template<> struct WT<float> {
  static __device__ __forceinline__ float ld(const void* p, size_t i) {
    return ((const float*)p)[i];
  }
  static __device__ __forceinline__ void ld4(const void* p, size_t i, float* d) {
    const float4 v = *(const float4*)((const float*)p + i);
    d[0]=v.x; d[1]=v.y; d[2]=v.z; d[3]=v.w;
  }
};

// ---- 8-element bf16-fragment loads: direct (ushort) or fp32->bf16 convert ----
template<typename T> struct LD8;
template<> struct LD8<unsigned short> {
  static __device__ __forceinline__ short8 ld(const void* p, size_t i) {
    return *(const short8*)((const unsigned short*)p + i);
  }
  static __device__ __forceinline__ float lds(const void* p, size_t i) {
    return bf2f(((const unsigned short*)p)[i]);
  }
};
template<> struct LD8<float> {
  static __device__ __forceinline__ short8 ld(const void* p, size_t i) {
    const float* fp = (const float*)p + i;
    float4 f0 = *(const float4*)fp;
    float4 f1 = *(const float4*)(fp + 4);
    short8 v;
    v[0]=(short)f2bfbits(f0.x); v[1]=(short)f2bfbits(f0.y);
    v[2]=(short)f2bfbits(f0.z); v[3]=(short)f2bfbits(f0.w);
    v[4]=(short)f2bfbits(f1.x); v[5]=(short)f2bfbits(f1.y);
    v[6]=(short)f2bfbits(f1.z); v[7]=(short)f2bfbits(f1.w);
    return v;
  }
  static __device__ __forceinline__ float lds(const void* p, size_t i) {
    return ((const float*)p)[i];
  }
};

// ---- dtype detect: low u16 of each u32 word of x ----
__global__ void detect_k(const unsigned int* __restrict__ x, int* __restrict__ flag) {
  int tid = threadIdx.x;
  int cnt = 0;
  for (int i = tid; i < 256; i += 64) {
    float a = fabsf(bf2f((unsigned short)(x[i] & 0xffffu)));
    if (a > 1e-3f && a < 10.f) cnt++;
  }
  for (int off = 32; off >= 1; off >>= 1) cnt += __shfl_xor(cnt, off);
  if (tid == 0) *flag = (cnt >= 128) ? 1 : 0;
}

// ---- unified MFMA GEMM: C = epi(A @ W^T + bias) ----
// Tile: 128 x BN (BN=128 or 64), BK=32, 4 waves, 16x16x32 bf16 MFMA.
// Requires M%128==0, N%BN==0, K%32==0 (all call sites exact — no masks).
// mode 0: fp32 store; 1: +bias, silu, bf16 store; 2: +bias, softplus, fp32 store.
template<typename TA, typename TW, int BN>
__device__ __forceinline__ void mfma_body(
    const void* __restrict__ Av, const void* __restrict__ Wv,
    const void* __restrict__ biasv, void* __restrict__ Cv,
    int K, int lda, int ldb, int ldc, int mode)
{
  constexpr int MI = (BN == 128) ? 4 : 2;     // m-frags per wave
  __shared__ unsigned short As[128*40];       // 32 data + 8 pad per row
  __shared__ unsigned short Bs[BN*40];
  const int tid = threadIdx.x;
  const int m0 = blockIdx.x * 128;
  const int n0 = blockIdx.y * BN;
  const int lane = tid & 63;
  const int wv = tid >> 6;
  const int wm = (BN == 128) ? (wv >> 1) * 64 : wv * 32;
  const int wn = (BN == 128) ? (wv & 1) * 64 : 0;
  const int lr = lane & 15, lg = lane >> 4;

  f32x4 acc[MI][4];
  #pragma unroll
  for (int i = 0; i < MI; ++i)
    #pragma unroll
    for (int j = 0; j < 4; ++j) acc[i][j] = (f32x4){0.f, 0.f, 0.f, 0.f};

  for (int k0 = 0; k0 < K; k0 += 32) {
    short8 ra[2], rb[BN/64];
    #pragma unroll
    for (int r = 0; r < 2; ++r) {
      int chunk = tid + r*256;
      int row = chunk >> 2, sub = (chunk & 3) * 8;
      ra[r] = LD8<TA>::ld(Av, (size_t)(m0 + row)*lda + k0 + sub);
    }
    #pragma unroll
    for (int r = 0; r < BN/64; ++r) {
      int chunk = tid + r*256;
      int row = chunk >> 2, sub = (chunk & 3) * 8;
      rb[r] = LD8<TW>::ld(Wv, (size_t)(n0 + row)*ldb + k0 + sub);
    }
    __syncthreads();                       // prior iter's frag reads done
    #pragma unroll
    for (int r = 0; r < 2; ++r) {
      int chunk = tid + r*256;
      int row = chunk >> 2, sub = (chunk & 3) * 8;
      *(short8*)&As[row*40 + sub] = ra[r];
    }
    #pragma unroll
    for (int r = 0; r < BN/64; ++r) {
      int chunk = tid + r*256;
      int row = chunk >> 2, sub = (chunk & 3) * 8;
      *(short8*)&Bs[row*40 + sub] = rb[r];
    }
    __syncthreads();
    short8 af[MI], bfr[4];
    #pragma unroll
    for (int i = 0; i < MI; ++i)
      af[i] = *(const short8*)&As[(wm + i*16 + lr)*40 + lg*8];
    #pragma unroll
    for (int j = 0; j < 4; ++j)
      bfr[j] = *(const short8*)&Bs[(wn + j*16 + lr)*40 + lg*8];
    #pragma unroll
    for (int i = 0; i < MI; ++i)
      #pragma unroll
      for (int j = 0; j < 4; ++j)
        acc[i][j] = __builtin_amdgcn_mfma_f32_16x16x32_bf16(af[i], bfr[j], acc[i][j], 0, 0, 0);
  }

  // C/D layout: col=lane&15, row=(lane>>4)*4+reg  [m89/m91 verified]
  #pragma unroll
  for (int j = 0; j < 4; ++j) {
    int gn = n0 + wn + j*16 + lr;
    float bv = 0.f;
    if (mode >= 1) bv = LD8<TW>::lds(biasv, gn);
    #pragma unroll
    for (int i = 0; i < MI; ++i) {
      #pragma unroll
      for (int r = 0; r < 4; ++r) {
        int gm = m0 + wm + i*16 + lg*4 + r;
        float v = acc[i][j][r];
        if (mode == 1) {
          v += bv; v = v * sigmoidf_(v);
          ((unsigned short*)Cv)[(size_t)gm*ldc + gn] = f2bfbits(v);
        } else if (mode == 2) {
          v += bv; v = (v > 20.f) ? v : log1pf(__expf(v));
          ((float*)Cv)[(size_t)gm*ldc + gn] = v;
        } else {
          ((float*)Cv)[(size_t)gm*ldc + gn] = v;
        }
      }
    }
  }
}

// A: always-bf16 workspace tensor; W: input dtype via flag
template<int BN>
__global__ __launch_bounds__(256) void gemm_a16_k(const void* A, const void* W,
    const void* bias, void* C, int K, int lda, int ldb, int ldc, int mode,
    const int* __restrict__ flag)
{
  if (*flag) mfma_body<unsigned short, unsigned short, BN>(A, W, bias, C, K, lda, ldb, ldc, mode);
  else       mfma_body<unsigned short, float, BN>(A, W, bias, C, K, lda, ldb, ldc, mode);
}
// A: fp32 workspace tensor; W: input dtype via flag
template<int BN>
__global__ __launch_bounds__(256) void gemm_a32_k(const void* A, const void* W,
    const void* bias, void* C, int K, int lda, int ldb, int ldc, int mode,
    const int* __restrict__ flag)
{
  if (*flag) mfma_body<float, unsigned short, BN>(A, W, bias, C, K, lda, ldb, ldc, mode);
  else       mfma_body<float, float, BN>(A, W, bias, C, K, lda, ldb, ldc, mode);
}
// A: raw input tensor (dtype = flag); W same
template<int BN>
__global__ __launch_bounds__(256) void gemm_ain_k(const void* A, const void* W,
    const void* bias, void* C, int K, int lda, int ldb, int ldc, int mode,
    const int* __restrict__ flag)
{
  if (*flag) mfma_body<unsigned short, unsigned short, BN>(A, W, bias, C, K, lda, ldb, ldc, mode);
  else       mfma_body<float, float, BN>(A, W, bias, C, K, lda, ldb, ldc, mode);
}

// ---- z (gate) at last token only; embed is bf16 workspace ----
__global__ __launch_bounds__(256) void zlast_k(const unsigned short* __restrict__ embed,
    const void* __restrict__ W_in, float* __restrict__ z_last, const int* __restrict__ flag)
{
  int b = blockIdx.x;
  __shared__ float e[DM];
  for (int i = threadIdx.x; i < DM; i += 256)
    e[i] = bf2f(embed[(size_t)(b*L_ + L_-1)*DM + i]);
  __syncthreads();
  int fl = *flag;
  if (fl) {
    const unsigned short* W = (const unsigned short*)W_in;
    for (int j = threadIdx.x; j < DI; j += 256) {
      const unsigned short* w = &W[(size_t)(DI + j)*DM];
      float acc = 0.f;
      for (int k = 0; k < DM; ++k) acc += e[k]*bf2f(w[k]);
      z_last[b*DI + j] = acc;
    }
  } else {
    const float* W = (const float*)W_in;
    for (int j = threadIdx.x; j < DI; j += 256) {
      const float* w = &W[(size_t)(DI + j)*DM];
      float acc = 0.f;
      for (int k = 0; k < DM; ++k) acc += e[k]*w[k];
      z_last[b*DI + j] = acc;
    }
  }
}

// ---- causal depthwise conv + silu ----
template<typename TWt>
__device__ __forceinline__ void conv_body(const float* __restrict__ xu,
    const void* __restrict__ conv_w, const void* __restrict__ conv_b,
    float* __restrict__ u)
{
  int bi = blockIdx.x;                    // 1024 blocks = b(16) x tc(16) x dchunk(4)
  int d  = (bi & 3)*256 + threadIdx.x;
  int tc = (bi >> 2) & 15;
  int b  = bi >> 6;
  float w[4];
  WT<TWt>::ld4(conv_w, (size_t)d*4, w);
  float bias = WT<TWt>::ld(conv_b, d);
  int t0 = tc*64;
  const float* base = xu + (size_t)b*L_*DI + d;
  float* ubase = u + (size_t)b*L_*DI + d;
  float xm3 = (t0-3 >= 0) ? base[(size_t)(t0-3)*DI] : 0.f;
  float xm2 = (t0-2 >= 0) ? base[(size_t)(t0-2)*DI] : 0.f;
  float xm1 = (t0-1 >= 0) ? base[(size_t)(t0-1)*DI] : 0.f;
  for (int t = t0; t < t0+64; ++t) {
    float cur = base[(size_t)t*DI];
    float v = w[0]*xm3 + w[1]*xm2 + w[2]*xm1 + w[3]*cur + bias;
    ubase[(size_t)t*DI] = v * sigmoidf_(v);
    xm3 = xm2; xm2 = xm1; xm1 = cur;
  }
}
__global__ __launch_bounds__(256) void conv_k(const float* xu, const void* conv_w,
    const void* conv_b, float* u, const int* __restrict__ flag)
{
  if (*flag) conv_body<bf16>(xu, conv_w, conv_b, u);
  else       conv_body<float>(xu, conv_w, conv_b, u);
}

// ---- selective scan v2: thread = (1 d, 4 n); serial recurrence, t-chunk 64,
//      register-prefetch double buffering; only last-token y needed ----
__global__ __launch_bounds__(256) void scan2_k(const float* __restrict__ delta,
    const float* __restrict__ u, const float* __restrict__ xdbl,
    const void* __restrict__ A_log, float* __restrict__ y_scan,
    const int* __restrict__ flag)
{
  const int b = blockIdx.x;
  const int d0 = blockIdx.y * 64;
  const int tid = threadIdx.x;
  const int dl = tid >> 2, nq = tid & 3;
  const int d = d0 + dl;
  const int fl = *flag;
  float a[4];
  #pragma unroll
  for (int j = 0; j < 4; ++j) {
    float al = fl ? bf2f(((const unsigned short*)A_log)[(size_t)d*NST + nq*4 + j])
                  : ((const float*)A_log)[(size_t)d*NST + nq*4 + j];
    a[j] = -__expf(al);
  }
  __shared__ float sD[64*64];
  __shared__ float sU[64*64];
  __shared__ float sB[64*16];
  float rD[16], rU[16], rB[4];
  // prefetch chunk 0
  #pragma unroll
  for (int i = 0; i < 16; ++i) {
    int idx = tid + i*256; int tt = idx >> 6, dd = idx & 63;
    size_t row = (size_t)(b*L_ + tt);
    rD[i] = delta[row*DI + d0 + dd];
    rU[i] = u[row*DI + d0 + dd];
  }
  #pragma unroll
  for (int i = 0; i < 4; ++i) {
    int idx = tid + i*256; int tt = idx >> 4, q = idx & 15;
    rB[i] = xdbl[(size_t)(b*L_ + tt)*64 + DTR + q];
  }
  float h[4] = {0.f, 0.f, 0.f, 0.f};
  for (int c = 0; c < 16; ++c) {
    __syncthreads();               // previous chunk's compute done
    #pragma unroll
    for (int i = 0; i < 16; ++i) {
      int idx = tid + i*256; int tt = idx >> 6, dd = idx & 63;
      sD[tt*64 + dd] = rD[i];
      sU[tt*64 + dd] = rU[i];
    }
    #pragma unroll
    for (int i = 0; i < 4; ++i) {
      int idx = tid + i*256; int tt = idx >> 4, q = idx & 15;
      sB[tt*16 + q] = rB[i];
    }
    __syncthreads();
    if (c < 15) {                  // prefetch next chunk while computing
      #pragma unroll
      for (int i = 0; i < 16; ++i) {
        int idx = tid + i*256; int tt = idx >> 6, dd = idx & 63;
        size_t row = (size_t)(b*L_ + (c+1)*64 + tt);
        rD[i] = delta[row*DI + d0 + dd];
        rU[i] = u[row*DI + d0 + dd];
      }
      #pragma unroll
      for (int i = 0; i < 4; ++i) {
        int idx = tid + i*256; int tt = idx >> 4, q = idx & 15;
        rB[i] = xdbl[(size_t)(b*L_ + (c+1)*64 + tt)*64 + DTR + q];
      }
    }
    #pragma unroll 4
    for (int t = 0; t < 64; ++t) {
      float dt = sD[t*64 + dl];
      float ut = sU[t*64 + dl];
      float4 Bv = *(const float4*)&sB[t*16 + nq*4];
      float g = dt * ut;
      h[0] = __expf(dt*a[0])*h[0] + g*Bv.x;
      h[1] = __expf(dt*a[1])*h[1] + g*Bv.y;
      h[2] = __expf(dt*a[2])*h[2] + g*Bv.z;
      h[3] = __expf(dt*a[3])*h[3] + g*Bv.w;
    }
  }
  float4 cv = *(const float4*)&xdbl[(size_t)(b*L_ + L_-1)*64 + DTR + NST + nq*4];
  float p = h[0]*cv.x + h[1]*cv.y + h[2]*cv.z + h[3]*cv.w;
  p += __shfl_xor(p, 1);
  p += __shfl_xor(p, 2);
  if (nq == 0) y_scan[b*DI + d] = p;
}

// ---- last-token epilogue: y*silu(z) -> W_out -> layernorm -> silu -> 17 heads ----
template<typename TWt>
__device__ __forceinline__ void head_body(const float* __restrict__ y_scan,
    const float* __restrict__ u, const float* __restrict__ z_last,
    const void* __restrict__ Dskip, const void* __restrict__ W_out,
    const void* __restrict__ W_critic, const void* __restrict__ b_critic,
    const void* __restrict__ W_amean, const void* __restrict__ b_amean,
    const void* __restrict__ W_astd, const void* __restrict__ b_astd,
    void* __restrict__ out)
{
  int b = blockIdx.x;
  int tid = threadIdx.x;
  __shared__ float yz[DI];
  __shared__ float nb[DM];
  __shared__ float w1[8], w2[8];
  for (int i = tid; i < DI; i += 512) {
    float ys = y_scan[b*DI + i] + u[(size_t)(b*L_ + L_-1)*DI + i] * WT<TWt>::ld(Dskip, i);
    float z = z_last[b*DI + i];
    yz[i] = ys * (z * sigmoidf_(z));
  }
  __syncthreads();
  float m = 0.f;
  {
    size_t roff = (size_t)tid * DI;
    for (int k = 0; k < DI; ++k) m += yz[k] * WT<TWt>::ld(W_out, roff + k);
  }
  float s1 = m, s2 = m*m;
  for (int off = 32; off >= 1; off >>= 1) { s1 += __shfl_xor(s1, off); s2 += __shfl_xor(s2, off); }
  int wid = tid >> 6, lane = tid & 63;
  if (lane == 0) { w1[wid] = s1; w2[wid] = s2; }
  __syncthreads();
  float t1 = 0.f, t2 = 0.f;
  for (int i = 0; i < 8; ++i) { t1 += w1[i]; t2 += w2[i]; }
  float mu  = t1 * (1.f/DM);
  float var = t2 * (1.f/DM) - mu*mu;
  float v = (m - mu) * rsqrtf(var + 1e-5f);
  nb[tid] = v * sigmoidf_(v);
  __syncthreads();
  for (int o = wid; o < 17; o += 8) {
    const void* w; size_t woff; float bias;
    if (o < 8)       { w = W_amean; woff = (size_t)o*DM;     bias = WT<TWt>::ld(b_amean, o); }
    else if (o < 16) { w = W_astd;  woff = (size_t)(o-8)*DM; bias = WT<TWt>::ld(b_astd, o-8); }
    else             { w = W_critic; woff = 0;               bias = WT<TWt>::ld(b_critic, 0); }
    float p = 0.f;
    for (int j = lane; j < DM; j += 64) p += nb[j] * WT<TWt>::ld(w, woff + j);
    for (int off = 32; off >= 1; off >>= 1) p += __shfl_xor(p, off);
    if (lane == 0) {
      float r = p + bias;
      int idx; float val;
      if (o < 8)       { idx = b*8 + o;           val = r; }
      else if (o < 16) { float ls = fminf(1.f, fmaxf(-1.f, r));
                         idx = 128 + b*8 + (o-8); val = expf(ls); }
      else             { idx = 256 + b;           val = r; }
      if (sizeof(TWt) == 2) ((bf16*)out)[idx] = __float2bfloat16(val);
      else                  ((float*)out)[idx] = val;
    }
  }
}
__global__ __launch_bounds__(512) void head_k(const float* y_scan, const float* u,
    const float* z_last, const void* Dskip, const void* W_out,
    const void* W_critic, const void* b_critic, const void* W_amean,
    const void* b_amean, const void* W_astd, const void* b_astd,
    void* out, const int* __restrict__ flag)
{
  if (*flag) head_body<bf16>(y_scan, u, z_last, Dskip, W_out, W_critic, b_critic,
                             W_amean, b_amean, W_astd, b_astd, out);
  else       head_body<float>(y_scan, u, z_last, Dskip, W_out, W_critic, b_critic,
                              W_amean, b_amean, W_astd, b_astd, out);
}

extern "C" void kernel_launch(void* const* d_in, const int* in_sizes, int n_in,
                              void* d_out, int out_size, void* d_ws, size_t ws_size,
                              hipStream_t stream)
{
  const void* x        = d_in[0];
  const void* W_emb    = d_in[1];
  const void* b_emb    = d_in[2];
  const void* W_in     = d_in[3];
  const void* conv_w   = d_in[4];
  const void* conv_b   = d_in[5];
  const void* W_xproj  = d_in[6];
  const void* W_dt     = d_in[7];
  const void* b_dt     = d_in[8];
  const void* A_log    = d_in[9];
  const void* Dskip    = d_in[10];
  const void* W_out    = d_in[11];
  const void* W_critic = d_in[12];
  const void* b_critic = d_in[13];
  const void* W_amean  = d_in[14];
  const void* b_amean  = d_in[15];
  const void* W_astd   = d_in[16];
  const void* b_astd   = d_in[17];

  // workspace: embed(bf16,16MB) + xu(64MB) + uu(64MB) + xdbl(4MB) + small = ~148 MB
  char* ws = (char*)d_ws;
  unsigned short* embed_bf = (unsigned short*)ws; ws += (size_t)ML*DM*2;
  float* xu    = (float*)ws; ws += (size_t)ML*DI*4;
  float* uu    = (float*)ws; ws += (size_t)ML*DI*4;
  float* xdbl  = (float*)ws; ws += (size_t)ML*64*4;
  float* zlast = (float*)ws; ws += (size_t)B_*DI*4;
  float* yscan = (float*)ws; ws += (size_t)B_*DI*4;
  int*   flag  = (int*)ws;   ws += 64;
  float* delta = xu;  // xu dead after conv; reuse for delta

  // 0. detect input dtype (bf16 vs fp32)
  detect_k<<<1, 64, 0, stream>>>((const unsigned int*)x, flag);
  // 1. embed = silu(x @ W_emb^T + b_emb) -> bf16   (M=16384, N=512, K=32)
  gemm_ain_k<128><<<dim3(ML/128, DM/128), 256, 0, stream>>>(
      x, W_emb, b_emb, embed_bf, 32, 32, 32, DM, 1, flag);
  // 2. xu = embed @ W_in[:DI]^T -> fp32   (M=16384, N=1024, K=512)
  gemm_a16_k<128><<<dim3(ML/128, DI/128), 256, 0, stream>>>(
      embed_bf, W_in, nullptr, xu, DM, DM, DM, DI, 0, flag);
  // 2b. z at last token only
  zlast_k<<<16, 256, 0, stream>>>(embed_bf, W_in, zlast, flag);
  // 3. u = silu(causal depthwise conv(xu)) -> fp32
  conv_k<<<1024, 256, 0, stream>>>(xu, conv_w, conv_b, uu, flag);
  // 4. x_dbl = u @ W_xproj^T -> fp32   (M=16384, N=64, K=1024; BN=64 tile)
  gemm_a32_k<64><<<dim3(ML/128, 1), 256, 0, stream>>>(
      uu, W_xproj, nullptr, xdbl, DI, DI, DI, 64, 0, flag);
  // 5. delta = softplus(x_dbl[:, :32] @ W_dt^T + b_dt) -> fp32 (overwrites xu)
  gemm_a32_k<128><<<dim3(ML/128, DI/128), 256, 0, stream>>>(
      xdbl, W_dt, b_dt, delta, 32, 64, 32, DI, 2, flag);
  // 6. selective scan -> y at last token
  scan2_k<<<dim3(B_, DI/64), 256, 0, stream>>>(delta, uu, xdbl, A_log, yscan, flag);
  // 7. gate, out-proj, layernorm, silu, heads
  head_k<<<16, 512, 0, stream>>>(yscan, uu, zlast, Dskip, W_out, W_critic, b_critic,
                                 W_amean, b_amean, W_astd, b_astd, (void*)d_out, flag);
}

// Round 6
// 469.364 us; speedup vs baseline: 1.4250x; 1.4250x over previous
//
#include <hip/hip_runtime.h>
#include <hip/hip_bf16.h>
#include <math.h>

// Problem constants (MambaAgent reference)
#define B_   16
#define L_   1024
#define DM   512          // D_MODEL
#define DI   1024         // D_INNER
#define NST  16           // D_STATE
#define DTR  32           // DT_RANK
#define ML   (B_*L_)      // 16384 rows

typedef __hip_bfloat16 bf16;
typedef __attribute__((ext_vector_type(8))) short short8;
typedef __attribute__((ext_vector_type(4))) float f32x4;

__device__ __forceinline__ float bf2f(unsigned short u) {
  union { unsigned int i; float f; } v; v.i = ((unsigned int)u) << 16; return v.f;
}
__device__ __forceinline__ unsigned short f2bfbits(float f) {
  bf16 h = __float2bfloat16(f);
  return *(unsigned short*)&h;
}
__device__ __forceinline__ float sigmoidf_(float v) { return 1.f/(1.f+__expf(-v)); }
// runtime-dtype scalar load (fl=1: bf16, fl=0: fp32)
__device__ __forceinline__ float ldf(const void* p, size_t i, int fl) {
  return fl ? bf2f(((const unsigned short*)p)[i]) : ((const float*)p)[i];
}

// ---- 8-element bf16-fragment loads: direct (ushort) or fp32->bf16 convert ----
template<typename T> struct LD8;
template<> struct LD8<unsigned short> {
  static __device__ __forceinline__ short8 ld(const void* p, size_t i) {
    return *(const short8*)((const unsigned short*)p + i);
  }
  static __device__ __forceinline__ float lds(const void* p, size_t i) {
    return bf2f(((const unsigned short*)p)[i]);
  }
};
template<> struct LD8<float> {
  static __device__ __forceinline__ short8 ld(const void* p, size_t i) {
    const float* fp = (const float*)p + i;
    float4 f0 = *(const float4*)fp;
    float4 f1 = *(const float4*)(fp + 4);
    short8 v;
    v[0]=(short)f2bfbits(f0.x); v[1]=(short)f2bfbits(f0.y);
    v[2]=(short)f2bfbits(f0.z); v[3]=(short)f2bfbits(f0.w);
    v[4]=(short)f2bfbits(f1.x); v[5]=(short)f2bfbits(f1.y);
    v[6]=(short)f2bfbits(f1.z); v[7]=(short)f2bfbits(f1.w);
    return v;
  }
  static __device__ __forceinline__ float lds(const void* p, size_t i) {
    return ((const float*)p)[i];
  }
};

// ---- dtype detect: low u16 of each u32 word of x ----
__global__ void detect_k(const unsigned int* __restrict__ x, int* __restrict__ flag) {
  int tid = threadIdx.x;
  int cnt = 0;
  for (int i = tid; i < 256; i += 64) {
    float a = fabsf(bf2f((unsigned short)(x[i] & 0xffffu)));
    if (a > 1e-3f && a < 10.f) cnt++;
  }
  for (int off = 32; off >= 1; off >>= 1) cnt += __shfl_xor(cnt, off);
  if (tid == 0) *flag = (cnt >= 128) ? 1 : 0;
}

// ---- unified MFMA GEMM: C = epi(A @ W^T + bias) ----
// Tile: 128 x BN (BN=128 or 64), BK=32, 4 waves, 16x16x32 bf16 MFMA.
// Dynamic LDS (one buffer shared by both dtype instantiations).
// blockIdx.z = K-split index; per-split K passed; partial stored at z*csplit.
// mode 0: fp32 store; 1: +bias, silu, bf16 store; 3: plain bf16 store.
template<typename TA, typename TW, int BN>
__device__ __forceinline__ void mfma_body(
    const void* __restrict__ Av, const void* __restrict__ Wv,
    const void* __restrict__ biasv, void* __restrict__ Cv,
    int K, int lda, int ldb, int ldc, int mode, size_t csplit)
{
  extern __shared__ unsigned short smem[];
  unsigned short* As = smem;            // 128*40
  unsigned short* Bs = smem + 128*40;   // BN*40
  constexpr int MI = (BN == 128) ? 4 : 2;
  const int tid = threadIdx.x;
  const int m0 = blockIdx.x * 128;
  const int n0 = blockIdx.y * BN;
  const int kbase = blockIdx.z * K;
  const int lane = tid & 63;
  const int wv = tid >> 6;
  const int wm = (BN == 128) ? (wv >> 1) * 64 : wv * 32;
  const int wn = (BN == 128) ? (wv & 1) * 64 : 0;
  const int lr = lane & 15, lg = lane >> 4;

  f32x4 acc[MI][4];
  #pragma unroll
  for (int i = 0; i < MI; ++i)
    #pragma unroll
    for (int j = 0; j < 4; ++j) acc[i][j] = (f32x4){0.f, 0.f, 0.f, 0.f};

  for (int k0 = 0; k0 < K; k0 += 32) {
    short8 ra[2], rb[BN/64];
    #pragma unroll
    for (int r = 0; r < 2; ++r) {
      int chunk = tid + r*256;
      int row = chunk >> 2, sub = (chunk & 3) * 8;
      ra[r] = LD8<TA>::ld(Av, (size_t)(m0 + row)*lda + kbase + k0 + sub);
    }
    #pragma unroll
    for (int r = 0; r < BN/64; ++r) {
      int chunk = tid + r*256;
      int row = chunk >> 2, sub = (chunk & 3) * 8;
      rb[r] = LD8<TW>::ld(Wv, (size_t)(n0 + row)*ldb + kbase + k0 + sub);
    }
    __syncthreads();
    #pragma unroll
    for (int r = 0; r < 2; ++r) {
      int chunk = tid + r*256;
      int row = chunk >> 2, sub = (chunk & 3) * 8;
      *(short8*)&As[row*40 + sub] = ra[r];
    }
    #pragma unroll
    for (int r = 0; r < BN/64; ++r) {
      int chunk = tid + r*256;
      int row = chunk >> 2, sub = (chunk & 3) * 8;
      *(short8*)&Bs[row*40 + sub] = rb[r];
    }
    __syncthreads();
    short8 af[MI], bfr[4];
    #pragma unroll
    for (int i = 0; i < MI; ++i)
      af[i] = *(const short8*)&As[(wm + i*16 + lr)*40 + lg*8];
    #pragma unroll
    for (int j = 0; j < 4; ++j)
      bfr[j] = *(const short8*)&Bs[(wn + j*16 + lr)*40 + lg*8];
    #pragma unroll
    for (int i = 0; i < MI; ++i)
      #pragma unroll
      for (int j = 0; j < 4; ++j)
        acc[i][j] = __builtin_amdgcn_mfma_f32_16x16x32_bf16(af[i], bfr[j], acc[i][j], 0, 0, 0);
  }

  // C/D layout: col=lane&15, row=(lane>>4)*4+reg  [m89/m91 verified]
  size_t cz = (size_t)blockIdx.z * csplit;
  #pragma unroll
  for (int j = 0; j < 4; ++j) {
    int gn = n0 + wn + j*16 + lr;
    float bv = (mode == 1) ? LD8<TW>::lds(biasv, gn) : 0.f;
    #pragma unroll
    for (int i = 0; i < MI; ++i) {
      #pragma unroll
      for (int r = 0; r < 4; ++r) {
        int gm = m0 + wm + i*16 + lg*4 + r;
        float v = acc[i][j][r];
        if (mode == 1) {
          v += bv; v = v * sigmoidf_(v);
          ((unsigned short*)Cv)[cz + (size_t)gm*ldc + gn] = f2bfbits(v);
        } else if (mode == 3) {
          ((unsigned short*)Cv)[cz + (size_t)gm*ldc + gn] = f2bfbits(v);
        } else {
          ((float*)Cv)[cz + (size_t)gm*ldc + gn] = v;
        }
      }
    }
  }
}

// A: raw input tensor (dtype = flag); W same dtype
template<int BN>
__global__ __launch_bounds__(256) void gemm_ain_k(const void* A, const void* W,
    const void* bias, void* C, int K, int lda, int ldb, int ldc, int mode,
    size_t csplit, const int* __restrict__ flag)
{
  if (*flag) mfma_body<unsigned short, unsigned short, BN>(A, W, bias, C, K, lda, ldb, ldc, mode, csplit);
  else       mfma_body<float, float, BN>(A, W, bias, C, K, lda, ldb, ldc, mode, csplit);
}
// A: bf16 workspace tensor; W: input dtype via flag
template<int BN>
__global__ __launch_bounds__(256) void gemm_a16_k(const void* A, const void* W,
    const void* bias, void* C, int K, int lda, int ldb, int ldc, int mode,
    size_t csplit, const int* __restrict__ flag)
{
  if (*flag) mfma_body<unsigned short, unsigned short, BN>(A, W, bias, C, K, lda, ldb, ldc, mode, csplit);
  else       mfma_body<unsigned short, float, BN>(A, W, bias, C, K, lda, ldb, ldc, mode, csplit);
}

// ---- z (gate) at last token only; embed is bf16 workspace ----
__global__ __launch_bounds__(256) void zlast_k(const unsigned short* __restrict__ embed,
    const void* __restrict__ W_in, float* __restrict__ z_last, const int* __restrict__ flag)
{
  int b = blockIdx.x;
  __shared__ float e[DM];
  for (int i = threadIdx.x; i < DM; i += 256)
    e[i] = bf2f(embed[(size_t)(b*L_ + L_-1)*DM + i]);
  __syncthreads();
  int fl = *flag;
  if (fl) {
    const unsigned short* W = (const unsigned short*)W_in;
    for (int j = threadIdx.x; j < DI; j += 256) {
      const unsigned short* w = &W[(size_t)(DI + j)*DM];
      float acc = 0.f;
      for (int k = 0; k < DM; ++k) acc += e[k]*bf2f(w[k]);
      z_last[b*DI + j] = acc;
    }
  } else {
    const float* W = (const float*)W_in;
    for (int j = threadIdx.x; j < DI; j += 256) {
      const float* w = &W[(size_t)(DI + j)*DM];
      float acc = 0.f;
      for (int k = 0; k < DM; ++k) acc += e[k]*w[k];
      z_last[b*DI + j] = acc;
    }
  }
}

// ---- causal depthwise conv + silu: xu bf16 -> u bf16 ----
__global__ __launch_bounds__(256) void conv_k(const unsigned short* __restrict__ xu,
    const void* __restrict__ conv_w, const void* __restrict__ conv_b,
    unsigned short* __restrict__ u, const int* __restrict__ flag)
{
  int bi = blockIdx.x;                    // 1024 blocks = b(16) x tc(16) x dchunk(4)
  int d  = (bi & 3)*256 + threadIdx.x;
  int tc = (bi >> 2) & 15;
  int b  = bi >> 6;
  int fl = *flag;
  float w0 = ldf(conv_w, (size_t)d*4 + 0, fl);
  float w1 = ldf(conv_w, (size_t)d*4 + 1, fl);
  float w2 = ldf(conv_w, (size_t)d*4 + 2, fl);
  float w3 = ldf(conv_w, (size_t)d*4 + 3, fl);
  float bias = ldf(conv_b, d, fl);
  int t0 = tc*64;
  const unsigned short* base = xu + (size_t)b*L_*DI + d;
  unsigned short* ubase = u + (size_t)b*L_*DI + d;
  float xm3 = (t0-3 >= 0) ? bf2f(base[(size_t)(t0-3)*DI]) : 0.f;
  float xm2 = (t0-2 >= 0) ? bf2f(base[(size_t)(t0-2)*DI]) : 0.f;
  float xm1 = (t0-1 >= 0) ? bf2f(base[(size_t)(t0-1)*DI]) : 0.f;
  for (int t = t0; t < t0+64; ++t) {
    float cur = bf2f(base[(size_t)t*DI]);
    float v = w0*xm3 + w1*xm2 + w2*xm1 + w3*cur + bias;
    ubase[(size_t)t*DI] = f2bfbits(v * sigmoidf_(v));
    xm3 = xm2; xm2 = xm1; xm1 = cur;
  }
}

// ---- fused selective scan: delta GEMM (K=32) computed in-kernel ----
// thread = (dl 0..15, n 0..15); grid (16 b, 64 d-blocks) = 1024 blocks.
// xd = two split-K partials of xdbl (each ML*64 fp32), summed during staging.
__global__ __launch_bounds__(256) void scan_k(
    const unsigned short* __restrict__ u, const float* __restrict__ xd,
    const void* __restrict__ A_log, const void* __restrict__ W_dt,
    const void* __restrict__ b_dt, float* __restrict__ y_scan,
    const int* __restrict__ flag)
{
  const int b = blockIdx.x;
  const int d0 = blockIdx.y * 16;
  const int tid = threadIdx.x;
  const int n = tid & 15, dl = tid >> 4;
  const int fl = *flag;
  __shared__ float sX[128*48];            // xdbl cols 0..47 (dt|B)
  __shared__ unsigned short sU[128*16];
  __shared__ float sDel[128*16];
  __shared__ float sW[16*33];             // W_dt rows (32) + b_dt (slot 32); pad 33
  for (int idx = tid; idx < 16*33; idx += 256) {
    int r = idx / 33, k = idx - r*33;
    sW[idx] = (k < 32) ? ldf(W_dt, (size_t)(d0+r)*DTR + k, fl)
                       : ldf(b_dt, d0 + r, fl);
  }
  float a = -__expf(ldf(A_log, (size_t)(d0+dl)*NST + n, fl));
  const float* p0 = xd;
  const float* p1 = xd + (size_t)ML*64;
  float4 rX[6]; unsigned int rU[4];
  // prefetch chunk 0
  #pragma unroll
  for (int i = 0; i < 6; ++i) {
    int f4 = tid + i*256; int row = f4 / 12, c4 = f4 - row*12;
    size_t g = (size_t)(b*L_ + row)*64 + c4*4;
    float4 x0 = *(const float4*)&p0[g];
    float4 x1 = *(const float4*)&p1[g];
    rX[i] = make_float4(x0.x+x1.x, x0.y+x1.y, x0.z+x1.z, x0.w+x1.w);
  }
  #pragma unroll
  for (int i = 0; i < 4; ++i) {
    int dw = tid + i*256; int row = dw >> 3, cp = (dw & 7)*2;
    rU[i] = *(const unsigned int*)&u[(size_t)(b*L_ + row)*DI + d0 + cp];
  }
  float h = 0.f;
  for (int c = 0; c < 8; ++c) {
    __syncthreads();                      // prev chunk's consumers done
    #pragma unroll
    for (int i = 0; i < 6; ++i) {
      int f4 = tid + i*256; int row = f4 / 12, c4 = f4 - row*12;
      *(float4*)&sX[row*48 + c4*4] = rX[i];
    }
    #pragma unroll
    for (int i = 0; i < 4; ++i) {
      int dw = tid + i*256;
      *(unsigned int*)&sU[dw*2] = rU[i];
    }
    __syncthreads();
    if (c < 7) {                          // prefetch next chunk
      #pragma unroll
      for (int i = 0; i < 6; ++i) {
        int f4 = tid + i*256; int row = f4 / 12, c4 = f4 - row*12;
        size_t g = (size_t)(b*L_ + (c+1)*128 + row)*64 + c4*4;
        float4 x0 = *(const float4*)&p0[g];
        float4 x1 = *(const float4*)&p1[g];
        rX[i] = make_float4(x0.x+x1.x, x0.y+x1.y, x0.z+x1.z, x0.w+x1.w);
      }
      #pragma unroll
      for (int i = 0; i < 4; ++i) {
        int dw = tid + i*256; int row = dw >> 3, cp = (dw & 7)*2;
        rU[i] = *(const unsigned int*)&u[(size_t)(b*L_ + (c+1)*128 + row)*DI + d0 + cp];
      }
    }
    // delta for this chunk: 8 (t,d) values per thread, 32-MAC dot + softplus
    #pragma unroll
    for (int i = 0; i < 8; ++i) {
      int v = tid + i*256; int t = v >> 4, dd = v & 15;
      const float* xr = &sX[t*48];
      const float* wr = &sW[dd*33];
      float acc = wr[32];
      #pragma unroll
      for (int k = 0; k < 32; ++k) acc += xr[k]*wr[k];
      sDel[t*16 + dd] = (acc > 20.f) ? acc : __logf(1.f + __expf(acc));
    }
    __syncthreads();
    #pragma unroll 4
    for (int t = 0; t < 128; ++t) {
      float dt = sDel[t*16 + dl];
      float ut = bf2f(sU[t*16 + dl]);
      float bn = sX[t*48 + 32 + n];
      h = __expf(dt*a)*h + (dt*ut)*bn;
    }
  }
  // y at last token: C from xdbl cols 48..63 (global, L2-hot)
  size_t gl = (size_t)(b*L_ + L_-1)*64 + 48 + n;
  float cn = p0[gl] + p1[gl];
  float p = h * cn;
  p += __shfl_xor(p, 1);
  p += __shfl_xor(p, 2);
  p += __shfl_xor(p, 4);
  p += __shfl_xor(p, 8);
  if (n == 0) y_scan[b*DI + d0 + dl] = p;
}

// ---- last-token epilogue: y*silu(z) -> W_out -> layernorm -> silu -> 17 heads ----
template<typename TWt>
__device__ __forceinline__ void head_body(const float* __restrict__ y_scan,
    const unsigned short* __restrict__ u, const float* __restrict__ z_last,
    const void* __restrict__ Dskip, const void* __restrict__ W_out,
    const void* __restrict__ W_critic, const void* __restrict__ b_critic,
    const void* __restrict__ W_amean, const void* __restrict__ b_amean,
    const void* __restrict__ W_astd, const void* __restrict__ b_astd,
    void* __restrict__ out, float* yz, float* nb, float* w1, float* w2)
{
  const int fl = (sizeof(TWt) == 2) ? 1 : 0;
  int b = blockIdx.x;
  int tid = threadIdx.x;
  for (int i = tid; i < DI; i += 512) {
    float ys = y_scan[b*DI + i] + bf2f(u[(size_t)(b*L_ + L_-1)*DI + i]) * ldf(Dskip, i, fl);
    float z = z_last[b*DI + i];
    yz[i] = ys * (z * sigmoidf_(z));
  }
  __syncthreads();
  float m = 0.f;
  {
    size_t roff = (size_t)tid * DI;
    for (int k = 0; k < DI; ++k) m += yz[k] * ldf(W_out, roff + k, fl);
  }
  float s1 = m, s2 = m*m;
  for (int off = 32; off >= 1; off >>= 1) { s1 += __shfl_xor(s1, off); s2 += __shfl_xor(s2, off); }
  int wid = tid >> 6, lane = tid & 63;
  if (lane == 0) { w1[wid] = s1; w2[wid] = s2; }
  __syncthreads();
  float t1 = 0.f, t2 = 0.f;
  for (int i = 0; i < 8; ++i) { t1 += w1[i]; t2 += w2[i]; }
  float mu  = t1 * (1.f/DM);
  float var = t2 * (1.f/DM) - mu*mu;
  float v = (m - mu) * rsqrtf(var + 1e-5f);
  nb[tid] = v * sigmoidf_(v);
  __syncthreads();
  for (int o = wid; o < 17; o += 8) {
    const void* w; size_t woff; float bias;
    if (o < 8)       { w = W_amean; woff = (size_t)o*DM;     bias = ldf(b_amean, o, fl); }
    else if (o < 16) { w = W_astd;  woff = (size_t)(o-8)*DM; bias = ldf(b_astd, o-8, fl); }
    else             { w = W_critic; woff = 0;               bias = ldf(b_critic, 0, fl); }
    float p = 0.f;
    for (int j = lane; j < DM; j += 64) p += nb[j] * ldf(w, woff + j, fl);
    for (int off = 32; off >= 1; off >>= 1) p += __shfl_xor(p, off);
    if (lane == 0) {
      float r = p + bias;
      int idx; float val;
      if (o < 8)       { idx = b*8 + o;           val = r; }
      else if (o < 16) { float ls = fminf(1.f, fmaxf(-1.f, r));
                         idx = 128 + b*8 + (o-8); val = expf(ls); }
      else             { idx = 256 + b;           val = r; }
      if (fl) ((bf16*)out)[idx] = __float2bfloat16(val);
      else    ((float*)out)[idx] = val;
    }
  }
}
__global__ __launch_bounds__(512) void head_k(const float* y_scan, const unsigned short* u,
    const float* z_last, const void* Dskip, const void* W_out,
    const void* W_critic, const void* b_critic, const void* W_amean,
    const void* b_amean, const void* W_astd, const void* b_astd,
    void* out, const int* __restrict__ flag)
{
  __shared__ float yz[DI];
  __shared__ float nb[DM];
  __shared__ float w1[8], w2[8];
  if (*flag) head_body<bf16>(y_scan, u, z_last, Dskip, W_out, W_critic, b_critic,
                             W_amean, b_amean, W_astd, b_astd, out, yz, nb, w1, w2);
  else       head_body<float>(y_scan, u, z_last, Dskip, W_out, W_critic, b_critic,
                              W_amean, b_amean, W_astd, b_astd, out, yz, nb, w1, w2);
}

extern "C" void kernel_launch(void* const* d_in, const int* in_sizes, int n_in,
                              void* d_out, int out_size, void* d_ws, size_t ws_size,
                              hipStream_t stream)
{
  const void* x        = d_in[0];
  const void* W_emb    = d_in[1];
  const void* b_emb    = d_in[2];
  const void* W_in     = d_in[3];
  const void* conv_w   = d_in[4];
  const void* conv_b   = d_in[5];
  const void* W_xproj  = d_in[6];
  const void* W_dt     = d_in[7];
  const void* b_dt     = d_in[8];
  const void* A_log    = d_in[9];
  const void* Dskip    = d_in[10];
  const void* W_out    = d_in[11];
  const void* W_critic = d_in[12];
  const void* b_critic = d_in[13];
  const void* W_amean  = d_in[14];
  const void* b_amean  = d_in[15];
  const void* W_astd   = d_in[16];
  const void* b_astd   = d_in[17];

  // workspace: embed 16 MB + xu 32 MB + u 32 MB + xdbl2 8 MB + small = ~88 MB
  char* ws = (char*)d_ws;
  unsigned short* embed_bf = (unsigned short*)ws; ws += (size_t)ML*DM*2;
  unsigned short* xu_b = (unsigned short*)ws; ws += (size_t)ML*DI*2;
  unsigned short* u_b  = (unsigned short*)ws; ws += (size_t)ML*DI*2;
  float* xdbl2 = (float*)ws; ws += (size_t)2*ML*64*4;
  float* zlast = (float*)ws; ws += (size_t)B_*DI*4;
  float* yscan = (float*)ws; ws += (size_t)B_*DI*4;
  int*   flag  = (int*)ws;   ws += 64;

  // 0. detect input dtype (bf16 vs fp32)
  detect_k<<<1, 64, 0, stream>>>((const unsigned int*)x, flag);
  // 1. embed = silu(x @ W_emb^T + b_emb) -> bf16   (M=16384, N=512, K=32)
  gemm_ain_k<128><<<dim3(ML/128, DM/128), 256, 256*40*2, stream>>>(
      x, W_emb, b_emb, embed_bf, 32, 32, 32, DM, 1, 0, flag);
  // 2. xu = embed @ W_in[:DI]^T -> bf16   (M=16384, N=1024, K=512)
  gemm_a16_k<128><<<dim3(ML/128, DI/128), 256, 256*40*2, stream>>>(
      embed_bf, W_in, nullptr, xu_b, DM, DM, DM, DI, 3, 0, flag);
  // 2b. z at last token only
  zlast_k<<<16, 256, 0, stream>>>(embed_bf, W_in, zlast, flag);
  // 3. u = silu(causal depthwise conv(xu)) -> bf16
  conv_k<<<1024, 256, 0, stream>>>(xu_b, conv_w, conv_b, u_b, flag);
  // 4. x_dbl = u @ W_xproj^T, split-K=2 -> two fp32 partials (summed in scan)
  gemm_a16_k<64><<<dim3(ML/128, 1, 2), 256, 192*40*2, stream>>>(
      u_b, W_xproj, nullptr, xdbl2, 512, DI, DI, 64, 0, (size_t)ML*64, flag);
  // 5. fused scan (delta GEMM inlined) -> y at last token
  scan_k<<<dim3(B_, DI/16), 256, 0, stream>>>(u_b, xdbl2, A_log, W_dt, b_dt, yscan, flag);
  // 6. gate, out-proj, layernorm, silu, heads
  head_k<<<16, 512, 0, stream>>>(yscan, u_b, zlast, Dskip, W_out, W_critic, b_critic,
                                 W_amean, b_amean, W_astd, b_astd, (void*)d_out, flag);
}

// Round 7
// 453.561 us; speedup vs baseline: 1.4747x; 1.0348x over previous
//
#include <hip/hip_runtime.h>
#include <hip/hip_bf16.h>
#include <math.h>

// Problem constants (MambaAgent reference)
#define B_   16
#define L_   1024
#define DM   512          // D_MODEL
#define DI   1024         // D_INNER
#define NST  16           // D_STATE
#define DTR  32           // DT_RANK
#define ML   (B_*L_)      // 16384 rows
#define NSEG 8            // scan t-segments (128 steps each)

typedef __hip_bfloat16 bf16;
typedef __attribute__((ext_vector_type(8))) short short8;
typedef __attribute__((ext_vector_type(4))) float f32x4;

__device__ __forceinline__ float bf2f(unsigned short u) {
  union { unsigned int i; float f; } v; v.i = ((unsigned int)u) << 16; return v.f;
}
__device__ __forceinline__ unsigned short f2bfbits(float f) {
  bf16 h = __float2bfloat16(f);
  return *(unsigned short*)&h;
}
__device__ __forceinline__ float sigmoidf_(float v) { return 1.f/(1.f+__expf(-v)); }
// runtime-dtype scalar load (fl=1: bf16, fl=0: fp32)
__device__ __forceinline__ float ldf(const void* p, size_t i, int fl) {
  return fl ? bf2f(((const unsigned short*)p)[i]) : ((const float*)p)[i];
}

// ---- 8-element bf16-fragment loads: direct (ushort) or fp32->bf16 convert ----
template<typename T> struct LD8;
template<> struct LD8<unsigned short> {
  static __device__ __forceinline__ short8 ld(const void* p, size_t i) {
    return *(const short8*)((const unsigned short*)p + i);
  }
  static __device__ __forceinline__ float lds(const void* p, size_t i) {
    return bf2f(((const unsigned short*)p)[i]);
  }
};
template<> struct LD8<float> {
  static __device__ __forceinline__ short8 ld(const void* p, size_t i) {
    const float* fp = (const float*)p + i;
    float4 f0 = *(const float4*)fp;
    float4 f1 = *(const float4*)(fp + 4);
    short8 v;
    v[0]=(short)f2bfbits(f0.x); v[1]=(short)f2bfbits(f0.y);
    v[2]=(short)f2bfbits(f0.z); v[3]=(short)f2bfbits(f0.w);
    v[4]=(short)f2bfbits(f1.x); v[5]=(short)f2bfbits(f1.y);
    v[6]=(short)f2bfbits(f1.z); v[7]=(short)f2bfbits(f1.w);
    return v;
  }
  static __device__ __forceinline__ float lds(const void* p, size_t i) {
    return ((const float*)p)[i];
  }
};

// ---- dtype detect: low u16 of each u32 word of x ----
__global__ void detect_k(const unsigned int* __restrict__ x, int* __restrict__ flag) {
  int tid = threadIdx.x;
  int cnt = 0;
  for (int i = tid; i < 256; i += 64) {
    float a = fabsf(bf2f((unsigned short)(x[i] & 0xffffu)));
    if (a > 1e-3f && a < 10.f) cnt++;
  }
  for (int off = 32; off >= 1; off >>= 1) cnt += __shfl_xor(cnt, off);
  if (tid == 0) *flag = (cnt >= 128) ? 1 : 0;
}

// ---- unified MFMA GEMM: C = epi(A @ W^T + bias) ----
// Tile: 128 x BN (BN=128 or 64), BK=32, 4 waves, 16x16x32 bf16 MFMA.
// Dynamic LDS (shared by both dtype instantiations).
// blockIdx.z = K-split index; partial stored at z*csplit.
// mode 0: fp32 store; 1: +bias, silu, bf16 store; 3: plain bf16 store.
template<typename TA, typename TW, int BN>
__device__ __forceinline__ void mfma_body(
    const void* __restrict__ Av, const void* __restrict__ Wv,
    const void* __restrict__ biasv, void* __restrict__ Cv,
    int K, int lda, int ldb, int ldc, int mode, size_t csplit)
{
  extern __shared__ unsigned short smem[];
  unsigned short* As = smem;            // 128*40
  unsigned short* Bs = smem + 128*40;   // BN*40
  constexpr int MI = (BN == 128) ? 4 : 2;
  const int tid = threadIdx.x;
  const int m0 = blockIdx.x * 128;
  const int n0 = blockIdx.y * BN;
  const int kbase = blockIdx.z * K;
  const int lane = tid & 63;
  const int wv = tid >> 6;
  const int wm = (BN == 128) ? (wv >> 1) * 64 : wv * 32;
  const int wn = (BN == 128) ? (wv & 1) * 64 : 0;
  const int lr = lane & 15, lg = lane >> 4;

  f32x4 acc[MI][4];
  #pragma unroll
  for (int i = 0; i < MI; ++i)
    #pragma unroll
    for (int j = 0; j < 4; ++j) acc[i][j] = (f32x4){0.f, 0.f, 0.f, 0.f};

  for (int k0 = 0; k0 < K; k0 += 32) {
    short8 ra[2], rb[BN/64];
    #pragma unroll
    for (int r = 0; r < 2; ++r) {
      int chunk = tid + r*256;
      int row = chunk >> 2, sub = (chunk & 3) * 8;
      ra[r] = LD8<TA>::ld(Av, (size_t)(m0 + row)*lda + kbase + k0 + sub);
    }
    #pragma unroll
    for (int r = 0; r < BN/64; ++r) {
      int chunk = tid + r*256;
      int row = chunk >> 2, sub = (chunk & 3) * 8;
      rb[r] = LD8<TW>::ld(Wv, (size_t)(n0 + row)*ldb + kbase + k0 + sub);
    }
    __syncthreads();
    #pragma unroll
    for (int r = 0; r < 2; ++r) {
      int chunk = tid + r*256;
      int row = chunk >> 2, sub = (chunk & 3) * 8;
      *(short8*)&As[row*40 + sub] = ra[r];
    }
    #pragma unroll
    for (int r = 0; r < BN/64; ++r) {
      int chunk = tid + r*256;
      int row = chunk >> 2, sub = (chunk & 3) * 8;
      *(short8*)&Bs[row*40 + sub] = rb[r];
    }
    __syncthreads();
    short8 af[MI], bfr[4];
    #pragma unroll
    for (int i = 0; i < MI; ++i)
      af[i] = *(const short8*)&As[(wm + i*16 + lr)*40 + lg*8];
    #pragma unroll
    for (int j = 0; j < 4; ++j)
      bfr[j] = *(const short8*)&Bs[(wn + j*16 + lr)*40 + lg*8];
    #pragma unroll
    for (int i = 0; i < MI; ++i)
      #pragma unroll
      for (int j = 0; j < 4; ++j)
        acc[i][j] = __builtin_amdgcn_mfma_f32_16x16x32_bf16(af[i], bfr[j], acc[i][j], 0, 0, 0);
  }

  // C/D layout: col=lane&15, row=(lane>>4)*4+reg  [m89/m91 verified]
  size_t cz = (size_t)blockIdx.z * csplit;
  #pragma unroll
  for (int j = 0; j < 4; ++j) {
    int gn = n0 + wn + j*16 + lr;
    float bv = (mode == 1) ? LD8<TW>::lds(biasv, gn) : 0.f;
    #pragma unroll
    for (int i = 0; i < MI; ++i) {
      #pragma unroll
      for (int r = 0; r < 4; ++r) {
        int gm = m0 + wm + i*16 + lg*4 + r;
        float v = acc[i][j][r];
        if (mode == 1) {
          v += bv; v = v * sigmoidf_(v);
          ((unsigned short*)Cv)[cz + (size_t)gm*ldc + gn] = f2bfbits(v);
        } else if (mode == 3) {
          ((unsigned short*)Cv)[cz + (size_t)gm*ldc + gn] = f2bfbits(v);
        } else {
          ((float*)Cv)[cz + (size_t)gm*ldc + gn] = v;
        }
      }
    }
  }
}

// A: raw input tensor (dtype = flag); W same dtype
template<int BN>
__global__ __launch_bounds__(256) void gemm_ain_k(const void* A, const void* W,
    const void* bias, void* C, int K, int lda, int ldb, int ldc, int mode,
    size_t csplit, const int* __restrict__ flag)
{
  if (*flag) mfma_body<unsigned short, unsigned short, BN>(A, W, bias, C, K, lda, ldb, ldc, mode, csplit);
  else       mfma_body<float, float, BN>(A, W, bias, C, K, lda, ldb, ldc, mode, csplit);
}
// A: bf16 workspace tensor; W: input dtype via flag
template<int BN>
__global__ __launch_bounds__(256) void gemm_a16_k(const void* A, const void* W,
    const void* bias, void* C, int K, int lda, int ldb, int ldc, int mode,
    size_t csplit, const int* __restrict__ flag)
{
  if (*flag) mfma_body<unsigned short, unsigned short, BN>(A, W, bias, C, K, lda, ldb, ldc, mode, csplit);
  else       mfma_body<unsigned short, float, BN>(A, W, bias, C, K, lda, ldb, ldc, mode, csplit);
}

// ---- z (gate) at last token only; embed is bf16 workspace ----
__global__ __launch_bounds__(256) void zlast_k(const unsigned short* __restrict__ embed,
    const void* __restrict__ W_in, float* __restrict__ z_last, const int* __restrict__ flag)
{
  int b = blockIdx.x;
  __shared__ float e[DM];
  for (int i = threadIdx.x; i < DM; i += 256)
    e[i] = bf2f(embed[(size_t)(b*L_ + L_-1)*DM + i]);
  __syncthreads();
  int fl = *flag;
  if (fl) {
    const unsigned short* W = (const unsigned short*)W_in;
    for (int j = threadIdx.x; j < DI; j += 256) {
      const unsigned short* w = &W[(size_t)(DI + j)*DM];
      float acc = 0.f;
      for (int k = 0; k < DM; ++k) acc += e[k]*bf2f(w[k]);
      z_last[b*DI + j] = acc;
    }
  } else {
    const float* W = (const float*)W_in;
    for (int j = threadIdx.x; j < DI; j += 256) {
      const float* w = &W[(size_t)(DI + j)*DM];
      float acc = 0.f;
      for (int k = 0; k < DM; ++k) acc += e[k]*w[k];
      z_last[b*DI + j] = acc;
    }
  }
}

// ---- causal depthwise conv + silu: xu bf16 -> u bf16 ----
__global__ __launch_bounds__(256) void conv_k(const unsigned short* __restrict__ xu,
    const void* __restrict__ conv_w, const void* __restrict__ conv_b,
    unsigned short* __restrict__ u, const int* __restrict__ flag)
{
  int bi = blockIdx.x;                    // 1024 blocks = b(16) x tc(16) x dchunk(4)
  int d  = (bi & 3)*256 + threadIdx.x;
  int tc = (bi >> 2) & 15;
  int b  = bi >> 6;
  int fl = *flag;
  float w0 = ldf(conv_w, (size_t)d*4 + 0, fl);
  float w1 = ldf(conv_w, (size_t)d*4 + 1, fl);
  float w2 = ldf(conv_w, (size_t)d*4 + 2, fl);
  float w3 = ldf(conv_w, (size_t)d*4 + 3, fl);
  float bias = ldf(conv_b, d, fl);
  int t0 = tc*64;
  const unsigned short* base = xu + (size_t)b*L_*DI + d;
  unsigned short* ubase = u + (size_t)b*L_*DI + d;
  float xm3 = (t0-3 >= 0) ? bf2f(base[(size_t)(t0-3)*DI]) : 0.f;
  float xm2 = (t0-2 >= 0) ? bf2f(base[(size_t)(t0-2)*DI]) : 0.f;
  float xm1 = (t0-1 >= 0) ? bf2f(base[(size_t)(t0-1)*DI]) : 0.f;
  for (int t = t0; t < t0+64; ++t) {
    float cur = bf2f(base[(size_t)t*DI]);
    float v = w0*xm3 + w1*xm2 + w2*xm1 + w3*cur + bias;
    ubase[(size_t)t*DI] = f2bfbits(v * sigmoidf_(v));
    xm3 = xm2; xm2 = xm1; xm1 = cur;
  }
}

// ---- segmented selective scan, delta fused (linear recurrence => segmentable):
// segment result (P,S): h_full = P*h_in + S with P = exp(a*sum(dt)), S = local scan.
// grid (16 b, 64 dblk, NSEG seg); thread = (dl 0..15, n 0..15). ----
__global__ __launch_bounds__(256) void scan_seg_k(
    const unsigned short* __restrict__ u, const float* __restrict__ xd,
    const void* __restrict__ A_log, const void* __restrict__ W_dt,
    const void* __restrict__ b_dt, float2* __restrict__ ps,
    const int* __restrict__ flag)
{
  const int b = blockIdx.x;
  const int d0 = blockIdx.y * 16;
  const int t0g = blockIdx.z * (L_/NSEG);     // 128 steps per segment
  const int tid = threadIdx.x;
  const int n = tid & 15, dl = tid >> 4, dd = tid & 15;
  const int fl = *flag;
  __shared__ float sX[128*48];                // xdbl cols 0..47 (dt|B)
  __shared__ unsigned short sU[128*16];
  __shared__ float sDel[128*16];
  __shared__ float sW[16*36];                 // 32 W_dt + bias@32; row pad 36 (16B-aligned)
  for (int idx = tid; idx < 16*36; idx += 256) {
    int r = idx / 36, k = idx - r*36;
    float v = 0.f;
    if (k < 32) v = ldf(W_dt, (size_t)(d0+r)*DTR + k, fl);
    else if (k == 32) v = ldf(b_dt, d0 + r, fl);
    sW[idx] = v;
  }
  float a = -__expf(ldf(A_log, (size_t)(d0+dl)*NST + n, fl));
  const float* p0 = xd;
  const float* p1 = xd + (size_t)ML*64;
  // stage xdbl cols 0..47 (sum of split-K partials) + u for 128 rows
  #pragma unroll
  for (int i = 0; i < 6; ++i) {
    int f4 = tid + i*256; int row = f4 / 12, c4 = f4 - row*12;
    size_t g = (size_t)(b*L_ + t0g + row)*64 + c4*4;
    float4 x0 = *(const float4*)&p0[g];
    float4 x1 = *(const float4*)&p1[g];
    *(float4*)&sX[row*48 + c4*4] = make_float4(x0.x+x1.x, x0.y+x1.y, x0.z+x1.z, x0.w+x1.w);
  }
  #pragma unroll
  for (int i = 0; i < 4; ++i) {
    int dw = tid + i*256; int row = dw >> 3, cp = (dw & 7)*2;
    *(unsigned int*)&sU[row*16 + cp] =
        *(const unsigned int*)&u[(size_t)(b*L_ + t0g + row)*DI + d0 + cp];
  }
  __syncthreads();
  // delta: 8 (t,dd) values per thread; dd fixed per thread, t = (tid>>4)+i*16
  {
    const float* wr = &sW[dd*36];
    float4 w0 = *(const float4*)&wr[0],  w1 = *(const float4*)&wr[4];
    float4 w2 = *(const float4*)&wr[8],  w3 = *(const float4*)&wr[12];
    float4 w4 = *(const float4*)&wr[16], w5 = *(const float4*)&wr[20];
    float4 w6 = *(const float4*)&wr[24], w7 = *(const float4*)&wr[28];
    float bias = wr[32];
    #pragma unroll
    for (int i = 0; i < 8; ++i) {
      int t = (tid >> 4) + i*16;
      const float* xr = &sX[t*48];
      float4 x0 = *(const float4*)&xr[0],  x1 = *(const float4*)&xr[4];
      float4 x2 = *(const float4*)&xr[8],  x3 = *(const float4*)&xr[12];
      float4 x4 = *(const float4*)&xr[16], x5 = *(const float4*)&xr[20];
      float4 x6 = *(const float4*)&xr[24], x7 = *(const float4*)&xr[28];
      float acc = bias
        + x0.x*w0.x + x0.y*w0.y + x0.z*w0.z + x0.w*w0.w
        + x1.x*w1.x + x1.y*w1.y + x1.z*w1.z + x1.w*w1.w
        + x2.x*w2.x + x2.y*w2.y + x2.z*w2.z + x2.w*w2.w
        + x3.x*w3.x + x3.y*w3.y + x3.z*w3.z + x3.w*w3.w
        + x4.x*w4.x + x4.y*w4.y + x4.z*w4.z + x4.w*w4.w
        + x5.x*w5.x + x5.y*w5.y + x5.z*w5.z + x5.w*w5.w
        + x6.x*w6.x + x6.y*w6.y + x6.z*w6.z + x6.w*w6.w
        + x7.x*w7.x + x7.y*w7.y + x7.z*w7.z + x7.w*w7.w;
      sDel[t*16 + dd] = (acc > 20.f) ? acc : __logf(1.f + __expf(acc));
    }
  }
  __syncthreads();
  // local recurrence over 128 steps; track sum(dt) for P
  float h = 0.f, sdt = 0.f;
  #pragma unroll 4
  for (int t = 0; t < 128; ++t) {
    float dt = sDel[t*16 + dl];
    float ut = bf2f(sU[t*16 + dl]);
    float bn = sX[t*48 + 32 + n];
    h = __expf(dt*a)*h + (dt*ut)*bn;
    sdt += dt;
  }
  float P = __expf(a * sdt);
  ps[((size_t)(b*64 + blockIdx.y)*NSEG + blockIdx.z)*256 + tid] = make_float2(P, h);
}

// ---- fold segments + C-dot -> y at last token. grid (16 b, 64 dblk). ----
__global__ __launch_bounds__(256) void combine_k(const float2* __restrict__ ps,
    const float* __restrict__ xd, float* __restrict__ y_scan)
{
  int b = blockIdx.x, dblk = blockIdx.y;
  int tid = threadIdx.x;
  int n = tid & 15, dl = tid >> 4;
  size_t base = (size_t)(b*64 + dblk)*NSEG*256 + tid;
  float h = 0.f;
  #pragma unroll
  for (int s = 0; s < NSEG; ++s) {
    float2 v = ps[base + (size_t)s*256];
    h = v.x*h + v.y;
  }
  const float* p0 = xd;
  const float* p1 = xd + (size_t)ML*64;
  size_t gl = (size_t)(b*L_ + L_-1)*64 + 48 + n;
  float cn = p0[gl] + p1[gl];
  float p = h * cn;
  p += __shfl_xor(p, 1);
  p += __shfl_xor(p, 2);
  p += __shfl_xor(p, 4);
  p += __shfl_xor(p, 8);
  if (n == 0) y_scan[b*DI + dblk*16 + dl] = p;
}

// ---- last-token epilogue: y*silu(z) -> W_out -> layernorm -> silu -> 17 heads ----
template<typename TWt>
__device__ __forceinline__ void head_body(const float* __restrict__ y_scan,
    const unsigned short* __restrict__ u, const float* __restrict__ z_last,
    const void* __restrict__ Dskip, const void* __restrict__ W_out,
    const void* __restrict__ W_critic, const void* __restrict__ b_critic,
    const void* __restrict__ W_amean, const void* __restrict__ b_amean,
    const void* __restrict__ W_astd, const void* __restrict__ b_astd,
    void* __restrict__ out, float* yz, float* nb, float* w1, float* w2)
{
  const int fl = (sizeof(TWt) == 2) ? 1 : 0;
  int b = blockIdx.x;
  int tid = threadIdx.x;
  for (int i = tid; i < DI; i += 512) {
    float ys = y_scan[b*DI + i] + bf2f(u[(size_t)(b*L_ + L_-1)*DI + i]) * ldf(Dskip, i, fl);
    float z = z_last[b*DI + i];
    yz[i] = ys * (z * sigmoidf_(z));
  }
  __syncthreads();
  float m = 0.f;
  {
    size_t roff = (size_t)tid * DI;
    for (int k = 0; k < DI; ++k) m += yz[k] * ldf(W_out, roff + k, fl);
  }
  float s1 = m, s2 = m*m;
  for (int off = 32; off >= 1; off >>= 1) { s1 += __shfl_xor(s1, off); s2 += __shfl_xor(s2, off); }
  int wid = tid >> 6, lane = tid & 63;
  if (lane == 0) { w1[wid] = s1; w2[wid] = s2; }
  __syncthreads();
  float t1 = 0.f, t2 = 0.f;
  for (int i = 0; i < 8; ++i) { t1 += w1[i]; t2 += w2[i]; }
  float mu  = t1 * (1.f/DM);
  float var = t2 * (1.f/DM) - mu*mu;
  float v = (m - mu) * rsqrtf(var + 1e-5f);
  nb[tid] = v * sigmoidf_(v);
  __syncthreads();
  for (int o = wid; o < 17; o += 8) {
    const void* w; size_t woff; float bias;
    if (o < 8)       { w = W_amean; woff = (size_t)o*DM;     bias = ldf(b_amean, o, fl); }
    else if (o < 16) { w = W_astd;  woff = (size_t)(o-8)*DM; bias = ldf(b_astd, o-8, fl); }
    else             { w = W_critic; woff = 0;               bias = ldf(b_critic, 0, fl); }
    float p = 0.f;
    for (int j = lane; j < DM; j += 64) p += nb[j] * ldf(w, woff + j, fl);
    for (int off = 32; off >= 1; off >>= 1) p += __shfl_xor(p, off);
    if (lane == 0) {
      float r = p + bias;
      int idx; float val;
      if (o < 8)       { idx = b*8 + o;           val = r; }
      else if (o < 16) { float ls = fminf(1.f, fmaxf(-1.f, r));
                         idx = 128 + b*8 + (o-8); val = expf(ls); }
      else             { idx = 256 + b;           val = r; }
      if (fl) ((bf16*)out)[idx] = __float2bfloat16(val);
      else    ((float*)out)[idx] = val;
    }
  }
}
__global__ __launch_bounds__(512) void head_k(const float* y_scan, const unsigned short* u,
    const float* z_last, const void* Dskip, const void* W_out,
    const void* W_critic, const void* b_critic, const void* W_amean,
    const void* b_amean, const void* W_astd, const void* b_astd,
    void* out, const int* __restrict__ flag)
{
  __shared__ float yz[DI];
  __shared__ float nb[DM];
  __shared__ float w1[8], w2[8];
  if (*flag) head_body<bf16>(y_scan, u, z_last, Dskip, W_out, W_critic, b_critic,
                             W_amean, b_amean, W_astd, b_astd, out, yz, nb, w1, w2);
  else       head_body<float>(y_scan, u, z_last, Dskip, W_out, W_critic, b_critic,
                              W_amean, b_amean, W_astd, b_astd, out, yz, nb, w1, w2);
}

extern "C" void kernel_launch(void* const* d_in, const int* in_sizes, int n_in,
                              void* d_out, int out_size, void* d_ws, size_t ws_size,
                              hipStream_t stream)
{
  const void* x        = d_in[0];
  const void* W_emb    = d_in[1];
  const void* b_emb    = d_in[2];
  const void* W_in     = d_in[3];
  const void* conv_w   = d_in[4];
  const void* conv_b   = d_in[5];
  const void* W_xproj  = d_in[6];
  const void* W_dt     = d_in[7];
  const void* b_dt     = d_in[8];
  const void* A_log    = d_in[9];
  const void* Dskip    = d_in[10];
  const void* W_out    = d_in[11];
  const void* W_critic = d_in[12];
  const void* b_critic = d_in[13];
  const void* W_amean  = d_in[14];
  const void* b_amean  = d_in[15];
  const void* W_astd   = d_in[16];
  const void* b_astd   = d_in[17];

  // workspace: embed 16 + xu 32 + u 32 + xdbl2 8 + ps 16.8 + small ~= 105 MB
  char* ws = (char*)d_ws;
  unsigned short* embed_bf = (unsigned short*)ws; ws += (size_t)ML*DM*2;
  unsigned short* xu_b = (unsigned short*)ws; ws += (size_t)ML*DI*2;
  unsigned short* u_b  = (unsigned short*)ws; ws += (size_t)ML*DI*2;
  float* xdbl2 = (float*)ws; ws += (size_t)2*ML*64*4;
  float2* psbuf = (float2*)ws; ws += (size_t)16*64*NSEG*256*8;
  float* zlast = (float*)ws; ws += (size_t)B_*DI*4;
  float* yscan = (float*)ws; ws += (size_t)B_*DI*4;
  int*   flag  = (int*)ws;   ws += 64;

  // 0. detect input dtype (bf16 vs fp32)
  detect_k<<<1, 64, 0, stream>>>((const unsigned int*)x, flag);
  // 1. embed = silu(x @ W_emb^T + b_emb) -> bf16   (M=16384, N=512, K=32)
  gemm_ain_k<128><<<dim3(ML/128, DM/128), 256, 256*40*2, stream>>>(
      x, W_emb, b_emb, embed_bf, 32, 32, 32, DM, 1, 0, flag);
  // 2. xu = embed @ W_in[:DI]^T -> bf16   (M=16384, N=1024, K=512)
  gemm_a16_k<128><<<dim3(ML/128, DI/128), 256, 256*40*2, stream>>>(
      embed_bf, W_in, nullptr, xu_b, DM, DM, DM, DI, 3, 0, flag);
  // 2b. z at last token only
  zlast_k<<<16, 256, 0, stream>>>(embed_bf, W_in, zlast, flag);
  // 3. u = silu(causal depthwise conv(xu)) -> bf16
  conv_k<<<1024, 256, 0, stream>>>(xu_b, conv_w, conv_b, u_b, flag);
  // 4. x_dbl = u @ W_xproj^T, split-K=2 -> two fp32 partials (summed in scan)
  gemm_a16_k<64><<<dim3(ML/128, 1, 2), 256, 192*40*2, stream>>>(
      u_b, W_xproj, nullptr, xdbl2, 512, DI, DI, 64, 0, (size_t)ML*64, flag);
  // 5. segmented fused scan -> per-segment (P,S)
  scan_seg_k<<<dim3(B_, DI/16, NSEG), 256, 0, stream>>>(
      u_b, xdbl2, A_log, W_dt, b_dt, psbuf, flag);
  // 5b. fold segments + C-dot -> y at last token
  combine_k<<<dim3(B_, DI/16), 256, 0, stream>>>(psbuf, xdbl2, yscan);
  // 6. gate, out-proj, layernorm, silu, heads
  head_k<<<16, 512, 0, stream>>>(yscan, u_b, zlast, Dskip, W_out, W_critic, b_critic,
                                 W_amean, b_amean, W_astd, b_astd, (void*)d_out, flag);
}

// Round 8
// 375.665 us; speedup vs baseline: 1.7804x; 1.2074x over previous
//
#include <hip/hip_runtime.h>
#include <hip/hip_bf16.h>
#include <math.h>

// Problem constants (MambaAgent reference)
#define B_   16
#define L_   1024
#define DM   512          // D_MODEL
#define DI   1024         // D_INNER
#define NST  16           // D_STATE
#define DTR  32           // DT_RANK
#define ML   (B_*L_)      // 16384 rows
#define SEGT 64           // t-steps per scan segment
#define NSEG (L_/SEGT)    // 16

typedef __hip_bfloat16 bf16;
typedef __attribute__((ext_vector_type(8))) short short8;
typedef __attribute__((ext_vector_type(4))) float f32x4;

__device__ __forceinline__ float bf2f(unsigned short u) {
  union { unsigned int i; float f; } v; v.i = ((unsigned int)u) << 16; return v.f;
}
__device__ __forceinline__ unsigned short f2bfbits(float f) {
  bf16 h = __float2bfloat16(f);
  return *(unsigned short*)&h;
}
__device__ __forceinline__ float sigmoidf_(float v) { return 1.f/(1.f+__expf(-v)); }
// runtime-dtype scalar load (fl=1: bf16, fl=0: fp32)
__device__ __forceinline__ float ldf(const void* p, size_t i, int fl) {
  return fl ? bf2f(((const unsigned short*)p)[i]) : ((const float*)p)[i];
}

// ---- 8-element bf16-fragment loads: direct (ushort) or fp32->bf16 convert ----
template<typename T> struct LD8;
template<> struct LD8<unsigned short> {
  static __device__ __forceinline__ short8 ld(const void* p, size_t i) {
    return *(const short8*)((const unsigned short*)p + i);
  }
  static __device__ __forceinline__ float lds(const void* p, size_t i) {
    return bf2f(((const unsigned short*)p)[i]);
  }
};
template<> struct LD8<float> {
  static __device__ __forceinline__ short8 ld(const void* p, size_t i) {
    const float* fp = (const float*)p + i;
    float4 f0 = *(const float4*)fp;
    float4 f1 = *(const float4*)(fp + 4);
    short8 v;
    v[0]=(short)f2bfbits(f0.x); v[1]=(short)f2bfbits(f0.y);
    v[2]=(short)f2bfbits(f0.z); v[3]=(short)f2bfbits(f0.w);
    v[4]=(short)f2bfbits(f1.x); v[5]=(short)f2bfbits(f1.y);
    v[6]=(short)f2bfbits(f1.z); v[7]=(short)f2bfbits(f1.w);
    return v;
  }
  static __device__ __forceinline__ float lds(const void* p, size_t i) {
    return ((const float*)p)[i];
  }
};

// ---- dtype detect: low u16 of each u32 word of x ----
__global__ void detect_k(const unsigned int* __restrict__ x, int* __restrict__ flag) {
  int tid = threadIdx.x;
  int cnt = 0;
  for (int i = tid; i < 256; i += 64) {
    float a = fabsf(bf2f((unsigned short)(x[i] & 0xffffu)));
    if (a > 1e-3f && a < 10.f) cnt++;
  }
  for (int off = 32; off >= 1; off >>= 1) cnt += __shfl_xor(cnt, off);
  if (tid == 0) *flag = (cnt >= 128) ? 1 : 0;
}

// ---- unified MFMA GEMM: C = epi(A @ W^T + bias) ----
// Tile: 128 x BN (BN=128 or 64), BK=32, 4 waves, 16x16x32 bf16 MFMA.
// Dynamic LDS; blockIdx.z = K-split index; partial stored at z*csplit.
// mode 0: fp32 store; 1: +bias, silu, bf16 store; 3: plain bf16 store.
template<typename TA, typename TW, int BN>
__device__ __forceinline__ void mfma_body(
    const void* __restrict__ Av, const void* __restrict__ Wv,
    const void* __restrict__ biasv, void* __restrict__ Cv,
    int K, int lda, int ldb, int ldc, int mode, size_t csplit)
{
  extern __shared__ unsigned short smem[];
  unsigned short* As = smem;            // 128*40
  unsigned short* Bs = smem + 128*40;   // BN*40
  constexpr int MI = (BN == 128) ? 4 : 2;
  const int tid = threadIdx.x;
  const int m0 = blockIdx.x * 128;
  const int n0 = blockIdx.y * BN;
  const int kbase = blockIdx.z * K;
  const int lane = tid & 63;
  const int wv = tid >> 6;
  const int wm = (BN == 128) ? (wv >> 1) * 64 : wv * 32;
  const int wn = (BN == 128) ? (wv & 1) * 64 : 0;
  const int lr = lane & 15, lg = lane >> 4;

  f32x4 acc[MI][4];
  #pragma unroll
  for (int i = 0; i < MI; ++i)
    #pragma unroll
    for (int j = 0; j < 4; ++j) acc[i][j] = (f32x4){0.f, 0.f, 0.f, 0.f};

  for (int k0 = 0; k0 < K; k0 += 32) {
    short8 ra[2], rb[BN/64];
    #pragma unroll
    for (int r = 0; r < 2; ++r) {
      int chunk = tid + r*256;
      int row = chunk >> 2, sub = (chunk & 3) * 8;
      ra[r] = LD8<TA>::ld(Av, (size_t)(m0 + row)*lda + kbase + k0 + sub);
    }
    #pragma unroll
    for (int r = 0; r < BN/64; ++r) {
      int chunk = tid + r*256;
      int row = chunk >> 2, sub = (chunk & 3) * 8;
      rb[r] = LD8<TW>::ld(Wv, (size_t)(n0 + row)*ldb + kbase + k0 + sub);
    }
    __syncthreads();
    #pragma unroll
    for (int r = 0; r < 2; ++r) {
      int chunk = tid + r*256;
      int row = chunk >> 2, sub = (chunk & 3) * 8;
      *(short8*)&As[row*40 + sub] = ra[r];
    }
    #pragma unroll
    for (int r = 0; r < BN/64; ++r) {
      int chunk = tid + r*256;
      int row = chunk >> 2, sub = (chunk & 3) * 8;
      *(short8*)&Bs[row*40 + sub] = rb[r];
    }
    __syncthreads();
    short8 af[MI], bfr[4];
    #pragma unroll
    for (int i = 0; i < MI; ++i)
      af[i] = *(const short8*)&As[(wm + i*16 + lr)*40 + lg*8];
    #pragma unroll
    for (int j = 0; j < 4; ++j)
      bfr[j] = *(const short8*)&Bs[(wn + j*16 + lr)*40 + lg*8];
    #pragma unroll
    for (int i = 0; i < MI; ++i)
      #pragma unroll
      for (int j = 0; j < 4; ++j)
        acc[i][j] = __builtin_amdgcn_mfma_f32_16x16x32_bf16(af[i], bfr[j], acc[i][j], 0, 0, 0);
  }

  // C/D layout: col=lane&15, row=(lane>>4)*4+reg  [m89/m91 verified]
  size_t cz = (size_t)blockIdx.z * csplit;
  #pragma unroll
  for (int j = 0; j < 4; ++j) {
    int gn = n0 + wn + j*16 + lr;
    float bv = (mode == 1) ? LD8<TW>::lds(biasv, gn) : 0.f;
    #pragma unroll
    for (int i = 0; i < MI; ++i) {
      #pragma unroll
      for (int r = 0; r < 4; ++r) {
        int gm = m0 + wm + i*16 + lg*4 + r;
        float v = acc[i][j][r];
        if (mode == 1) {
          v += bv; v = v * sigmoidf_(v);
          ((unsigned short*)Cv)[cz + (size_t)gm*ldc + gn] = f2bfbits(v);
        } else if (mode == 3) {
          ((unsigned short*)Cv)[cz + (size_t)gm*ldc + gn] = f2bfbits(v);
        } else {
          ((float*)Cv)[cz + (size_t)gm*ldc + gn] = v;
        }
      }
    }
  }
}

template<int BN>
__global__ __launch_bounds__(256) void gemm_ain_k(const void* A, const void* W,
    const void* bias, void* C, int K, int lda, int ldb, int ldc, int mode,
    size_t csplit, const int* __restrict__ flag)
{
  if (*flag) mfma_body<unsigned short, unsigned short, BN>(A, W, bias, C, K, lda, ldb, ldc, mode, csplit);
  else       mfma_body<float, float, BN>(A, W, bias, C, K, lda, ldb, ldc, mode, csplit);
}
template<int BN>
__global__ __launch_bounds__(256) void gemm_a16_k(const void* A, const void* W,
    const void* bias, void* C, int K, int lda, int ldb, int ldc, int mode,
    size_t csplit, const int* __restrict__ flag)
{
  if (*flag) mfma_body<unsigned short, unsigned short, BN>(A, W, bias, C, K, lda, ldb, ldc, mode, csplit);
  else       mfma_body<unsigned short, float, BN>(A, W, bias, C, K, lda, ldb, ldc, mode, csplit);
}

// ---- z (gate) at last token; grid (16 b, 4 jchunk); vectorized W loads ----
__global__ __launch_bounds__(256) void zlast_k(const unsigned short* __restrict__ embed,
    const void* __restrict__ W_in, float* __restrict__ z_last, const int* __restrict__ flag)
{
  int b = blockIdx.x;
  int j = blockIdx.y * 256 + threadIdx.x;
  __shared__ float e[DM];
  for (int i = threadIdx.x; i < DM; i += 256)
    e[i] = bf2f(embed[(size_t)(b*L_ + L_-1)*DM + i]);
  __syncthreads();
  int fl = *flag;
  float acc = 0.f;
  if (fl) {
    const unsigned short* w = (const unsigned short*)W_in + (size_t)(DI + j)*DM;
    for (int k = 0; k < DM; k += 8) {
      short8 v = *(const short8*)&w[k];
      acc += e[k+0]*bf2f((unsigned short)v[0]) + e[k+1]*bf2f((unsigned short)v[1])
           + e[k+2]*bf2f((unsigned short)v[2]) + e[k+3]*bf2f((unsigned short)v[3])
           + e[k+4]*bf2f((unsigned short)v[4]) + e[k+5]*bf2f((unsigned short)v[5])
           + e[k+6]*bf2f((unsigned short)v[6]) + e[k+7]*bf2f((unsigned short)v[7]);
    }
  } else {
    const float* w = (const float*)W_in + (size_t)(DI + j)*DM;
    for (int k = 0; k < DM; k += 4) {
      float4 v = *(const float4*)&w[k];
      acc += e[k]*v.x + e[k+1]*v.y + e[k+2]*v.z + e[k+3]*v.w;
    }
  }
  z_last[b*DI + j] = acc;
}

// ---- causal depthwise conv + silu: xu bf16 -> u bf16 ----
__global__ __launch_bounds__(256) void conv_k(const unsigned short* __restrict__ xu,
    const void* __restrict__ conv_w, const void* __restrict__ conv_b,
    unsigned short* __restrict__ u, const int* __restrict__ flag)
{
  int bi = blockIdx.x;                    // 1024 blocks = b(16) x tc(16) x dchunk(4)
  int d  = (bi & 3)*256 + threadIdx.x;
  int tc = (bi >> 2) & 15;
  int b  = bi >> 6;
  int fl = *flag;
  float w0 = ldf(conv_w, (size_t)d*4 + 0, fl);
  float w1 = ldf(conv_w, (size_t)d*4 + 1, fl);
  float w2 = ldf(conv_w, (size_t)d*4 + 2, fl);
  float w3 = ldf(conv_w, (size_t)d*4 + 3, fl);
  float bias = ldf(conv_b, d, fl);
  int t0 = tc*64;
  const unsigned short* base = xu + (size_t)b*L_*DI + d;
  unsigned short* ubase = u + (size_t)b*L_*DI + d;
  float xm3 = (t0-3 >= 0) ? bf2f(base[(size_t)(t0-3)*DI]) : 0.f;
  float xm2 = (t0-2 >= 0) ? bf2f(base[(size_t)(t0-2)*DI]) : 0.f;
  float xm1 = (t0-1 >= 0) ? bf2f(base[(size_t)(t0-1)*DI]) : 0.f;
  for (int t = t0; t < t0+64; ++t) {
    float cur = bf2f(base[(size_t)t*DI]);
    float v = w0*xm3 + w1*xm2 + w2*xm1 + w3*cur + bias;
    ubase[(size_t)t*DI] = f2bfbits(v * sigmoidf_(v));
    xm3 = xm2; xm2 = xm1; xm1 = cur;
  }
}

// ---- scan v3: thread = 1 d with all 16 n in registers; delta fused per-thread.
// grid (16 b, 4 dchunk(256), NSEG); no inner barrier: stage SEGT rows, compute.
// Writes per-segment (P_n, S_n): h_full = P*h_in + S, P = exp(a_n * sum dt). ----
__global__ __launch_bounds__(256) void scan3_k(
    const unsigned short* __restrict__ u, const float* __restrict__ xd,
    const void* __restrict__ A_log, const void* __restrict__ W_dt,
    const void* __restrict__ b_dt, float2* __restrict__ ps,
    const int* __restrict__ flag)
{
  const int b = blockIdx.x;
  const int d0 = blockIdx.y * 256;
  const int seg = blockIdx.z;
  const int t0g = seg * SEGT;
  const int tid = threadIdx.x;
  const int d = d0 + tid;
  const int fl = *flag;
  __shared__ float sX[SEGT*48];             // xdbl cols 0..47 (dt-in | B), 12 KB
  __shared__ unsigned short sU[SEGT*256];   // u for 256 d's, 32 KB
  // stage sX: sum of split-K partials; 768 float4 / 256 threads = 3 each
  #pragma unroll
  for (int i = 0; i < 3; ++i) {
    int f4 = tid + i*256; int row = f4 / 12, c4 = f4 - row*12;
    size_t g = (size_t)(b*L_ + t0g + row)*64 + c4*4;
    float4 x0 = *(const float4*)&xd[g];
    float4 x1 = *(const float4*)&xd[(size_t)ML*64 + g];
    *(float4*)&sX[row*48 + c4*4] = make_float4(x0.x+x1.x, x0.y+x1.y, x0.z+x1.z, x0.w+x1.w);
  }
  // stage sU: 2048 ushort8 / 256 threads = 8 each
  #pragma unroll
  for (int i = 0; i < 8; ++i) {
    int c8 = tid + i*256; int row = c8 >> 5, cp = (c8 & 31)*8;
    *(short8*)&sU[row*256 + cp] =
        *(const short8*)&u[(size_t)(b*L_ + t0g + row)*DI + d0 + cp];
  }
  // per-thread constants: W_dt row (32), bias, a[16]
  float w[32];
  #pragma unroll
  for (int k = 0; k < 32; ++k) w[k] = ldf(W_dt, (size_t)d*DTR + k, fl);
  float bias = ldf(b_dt, d, fl);
  float a[16];
  #pragma unroll
  for (int n = 0; n < 16; ++n) a[n] = -__expf(ldf(A_log, (size_t)d*NST + n, fl));
  float h[16];
  #pragma unroll
  for (int n = 0; n < 16; ++n) h[n] = 0.f;
  float sdt = 0.f;
  __syncthreads();
  for (int t = 0; t < SEGT; ++t) {
    const float* xr = &sX[t*48];
    float acc = bias;
    #pragma unroll
    for (int k = 0; k < 32; ++k) acc += xr[k]*w[k];
    float dt = (acc > 20.f) ? acc : __logf(1.f + __expf(acc));
    float ut = bf2f(sU[t*256 + tid]);
    float g = dt * ut;
    sdt += dt;
    #pragma unroll
    for (int n = 0; n < 16; ++n)
      h[n] = __expf(dt*a[n])*h[n] + g*xr[32+n];
  }
  size_t base = ((size_t)((b*NSEG + seg)*1024 + d))*16;
  #pragma unroll
  for (int n = 0; n < 16; ++n)
    ps[base + n] = make_float2(__expf(a[n]*sdt), h[n]);
}

// ---- fold segments + C-dot -> y at last token. grid (16 b, 4 dchunk). ----
__global__ __launch_bounds__(256) void combine3_k(const float2* __restrict__ ps,
    const float* __restrict__ xd, float* __restrict__ y_scan)
{
  int b = blockIdx.x;
  int d = blockIdx.y * 256 + threadIdx.x;
  float h[16];
  #pragma unroll
  for (int n = 0; n < 16; ++n) h[n] = 0.f;
  for (int s = 0; s < NSEG; ++s) {
    size_t base = ((size_t)((b*NSEG + s)*1024 + d))*16;
    #pragma unroll
    for (int n = 0; n < 16; ++n) {
      float2 v = ps[base + n];
      h[n] = v.x*h[n] + v.y;
    }
  }
  size_t gl = (size_t)(b*L_ + L_-1)*64 + 48;
  float y = 0.f;
  #pragma unroll
  for (int n = 0; n < 16; ++n) {
    float cn = xd[gl + n] + xd[(size_t)ML*64 + gl + n];
    y += h[n]*cn;
  }
  y_scan[b*DI + d] = y;
}

// ---- last-token epilogue: y*silu(z) -> W_out -> layernorm -> silu -> 17 heads ----
__global__ __launch_bounds__(512) void head_k(const float* __restrict__ y_scan,
    const unsigned short* __restrict__ u, const float* __restrict__ z_last,
    const void* __restrict__ Dskip, const void* __restrict__ W_out,
    const void* __restrict__ W_critic, const void* __restrict__ b_critic,
    const void* __restrict__ W_amean, const void* __restrict__ b_amean,
    const void* __restrict__ W_astd, const void* __restrict__ b_astd,
    void* __restrict__ out, const int* __restrict__ flag)
{
  __shared__ float yz[DI];
  __shared__ float nb[DM];
  __shared__ float w1[8], w2[8];
  const int fl = *flag;
  int b = blockIdx.x;
  int tid = threadIdx.x;
  for (int i = tid; i < DI; i += 512) {
    float ys = y_scan[b*DI + i] + bf2f(u[(size_t)(b*L_ + L_-1)*DI + i]) * ldf(Dskip, i, fl);
    float z = z_last[b*DI + i];
    yz[i] = ys * (z * sigmoidf_(z));
  }
  __syncthreads();
  float m = 0.f;
  if (fl) {
    const unsigned short* w = (const unsigned short*)W_out + (size_t)tid*DI;
    for (int k = 0; k < DI; k += 8) {
      short8 v = *(const short8*)&w[k];
      m += yz[k+0]*bf2f((unsigned short)v[0]) + yz[k+1]*bf2f((unsigned short)v[1])
         + yz[k+2]*bf2f((unsigned short)v[2]) + yz[k+3]*bf2f((unsigned short)v[3])
         + yz[k+4]*bf2f((unsigned short)v[4]) + yz[k+5]*bf2f((unsigned short)v[5])
         + yz[k+6]*bf2f((unsigned short)v[6]) + yz[k+7]*bf2f((unsigned short)v[7]);
    }
  } else {
    const float* w = (const float*)W_out + (size_t)tid*DI;
    for (int k = 0; k < DI; k += 4) {
      float4 v = *(const float4*)&w[k];
      m += yz[k]*v.x + yz[k+1]*v.y + yz[k+2]*v.z + yz[k+3]*v.w;
    }
  }
  float s1 = m, s2 = m*m;
  for (int off = 32; off >= 1; off >>= 1) { s1 += __shfl_xor(s1, off); s2 += __shfl_xor(s2, off); }
  int wid = tid >> 6, lane = tid & 63;
  if (lane == 0) { w1[wid] = s1; w2[wid] = s2; }
  __syncthreads();
  float t1 = 0.f, t2 = 0.f;
  for (int i = 0; i < 8; ++i) { t1 += w1[i]; t2 += w2[i]; }
  float mu  = t1 * (1.f/DM);
  float var = t2 * (1.f/DM) - mu*mu;
  float v = (m - mu) * rsqrtf(var + 1e-5f);
  nb[tid] = v * sigmoidf_(v);
  __syncthreads();
  for (int o = wid; o < 17; o += 8) {
    const void* w; size_t woff; float bias;
    if (o < 8)       { w = W_amean; woff = (size_t)o*DM;     bias = ldf(b_amean, o, fl); }
    else if (o < 16) { w = W_astd;  woff = (size_t)(o-8)*DM; bias = ldf(b_astd, o-8, fl); }
    else             { w = W_critic; woff = 0;               bias = ldf(b_critic, 0, fl); }
    float p = 0.f;
    for (int j = lane; j < DM; j += 64) p += nb[j] * ldf(w, woff + j, fl);
    for (int off = 32; off >= 1; off >>= 1) p += __shfl_xor(p, off);
    if (lane == 0) {
      float r = p + bias;
      int idx; float val;
      if (o < 8)       { idx = b*8 + o;           val = r; }
      else if (o < 16) { float ls = fminf(1.f, fmaxf(-1.f, r));
                         idx = 128 + b*8 + (o-8); val = expf(ls); }
      else             { idx = 256 + b;           val = r; }
      if (fl) ((bf16*)out)[idx] = __float2bfloat16(val);
      else    ((float*)out)[idx] = val;
    }
  }
}

extern "C" void kernel_launch(void* const* d_in, const int* in_sizes, int n_in,
                              void* d_out, int out_size, void* d_ws, size_t ws_size,
                              hipStream_t stream)
{
  const void* x        = d_in[0];
  const void* W_emb    = d_in[1];
  const void* b_emb    = d_in[2];
  const void* W_in     = d_in[3];
  const void* conv_w   = d_in[4];
  const void* conv_b   = d_in[5];
  const void* W_xproj  = d_in[6];
  const void* W_dt     = d_in[7];
  const void* b_dt     = d_in[8];
  const void* A_log    = d_in[9];
  const void* Dskip    = d_in[10];
  const void* W_out    = d_in[11];
  const void* W_critic = d_in[12];
  const void* b_critic = d_in[13];
  const void* W_amean  = d_in[14];
  const void* b_amean  = d_in[15];
  const void* W_astd   = d_in[16];
  const void* b_astd   = d_in[17];

  // workspace: embed 16 + xu 32 + u 32 + xdbl2 8 + ps 33.5 + small ~= 122 MB
  char* ws = (char*)d_ws;
  unsigned short* embed_bf = (unsigned short*)ws; ws += (size_t)ML*DM*2;
  unsigned short* xu_b = (unsigned short*)ws; ws += (size_t)ML*DI*2;
  unsigned short* u_b  = (unsigned short*)ws; ws += (size_t)ML*DI*2;
  float* xdbl2 = (float*)ws; ws += (size_t)2*ML*64*4;
  float2* psbuf = (float2*)ws; ws += (size_t)B_*NSEG*DI*NST*8;
  float* zlast = (float*)ws; ws += (size_t)B_*DI*4;
  float* yscan = (float*)ws; ws += (size_t)B_*DI*4;
  int*   flag  = (int*)ws;   ws += 64;

  // 0. detect input dtype (bf16 vs fp32)
  detect_k<<<1, 64, 0, stream>>>((const unsigned int*)x, flag);
  // 1. embed = silu(x @ W_emb^T + b_emb) -> bf16   (M=16384, N=512, K=32)
  gemm_ain_k<128><<<dim3(ML/128, DM/128), 256, 256*40*2, stream>>>(
      x, W_emb, b_emb, embed_bf, 32, 32, 32, DM, 1, 0, flag);
  // 2. xu = embed @ W_in[:DI]^T -> bf16   (M=16384, N=1024, K=512)
  gemm_a16_k<128><<<dim3(ML/128, DI/128), 256, 256*40*2, stream>>>(
      embed_bf, W_in, nullptr, xu_b, DM, DM, DM, DI, 3, 0, flag);
  // 2b. z at last token only
  zlast_k<<<dim3(16, 4), 256, 0, stream>>>(embed_bf, W_in, zlast, flag);
  // 3. u = silu(causal depthwise conv(xu)) -> bf16
  conv_k<<<1024, 256, 0, stream>>>(xu_b, conv_w, conv_b, u_b, flag);
  // 4. x_dbl = u @ W_xproj^T, split-K=2 -> two fp32 partials (summed in scan)
  gemm_a16_k<64><<<dim3(ML/128, 1, 2), 256, 192*40*2, stream>>>(
      u_b, W_xproj, nullptr, xdbl2, 512, DI, DI, 64, 0, (size_t)ML*64, flag);
  // 5. segmented fused scan (16 n per thread) -> per-segment (P,S)
  scan3_k<<<dim3(B_, 4, NSEG), 256, 0, stream>>>(
      u_b, xdbl2, A_log, W_dt, b_dt, psbuf, flag);
  // 5b. fold segments + C-dot -> y at last token
  combine3_k<<<dim3(B_, 4), 256, 0, stream>>>(psbuf, xdbl2, yscan);
  // 6. gate, out-proj, layernorm, silu, heads
  head_k<<<16, 512, 0, stream>>>(yscan, u_b, zlast, Dskip, W_out, W_critic, b_critic,
                                 W_amean, b_amean, W_astd, b_astd, (void*)d_out, flag);
}

// Round 10
// 352.529 us; speedup vs baseline: 1.8973x; 1.0656x over previous
//
#include <hip/hip_runtime.h>
#include <hip/hip_bf16.h>
#include <math.h>

// Problem constants (MambaAgent reference)
#define B_   16
#define L_   1024
#define DM   512          // D_MODEL
#define DI   1024         // D_INNER
#define NST  16           // D_STATE
#define DTR  32           // DT_RANK
#define ML   (B_*L_)      // 16384 rows
#define SEGT 64           // t-steps per scan segment
#define NSEG (L_/SEGT)    // 16

typedef __hip_bfloat16 bf16;
typedef __attribute__((ext_vector_type(8))) short short8;
typedef __attribute__((ext_vector_type(4))) float f32x4;

__device__ __forceinline__ float bf2f(unsigned short u) {
  union { unsigned int i; float f; } v; v.i = ((unsigned int)u) << 16; return v.f;
}
__device__ __forceinline__ unsigned short f2bfbits(float f) {
  bf16 h = __float2bfloat16(f);
  return *(unsigned short*)&h;
}
__device__ __forceinline__ float sigmoidf_(float v) { return 1.f/(1.f+__expf(-v)); }
// runtime-dtype scalar load (fl=1: bf16, fl=0: fp32)
__device__ __forceinline__ float ldf(const void* p, size_t i, int fl) {
  return fl ? bf2f(((const unsigned short*)p)[i]) : ((const float*)p)[i];
}

// ---- 8-element bf16-fragment loads: direct (ushort) or fp32->bf16 convert ----
template<typename T> struct LD8;
template<> struct LD8<unsigned short> {
  static __device__ __forceinline__ short8 ld(const void* p, size_t i) {
    return *(const short8*)((const unsigned short*)p + i);
  }
  static __device__ __forceinline__ float lds(const void* p, size_t i) {
    return bf2f(((const unsigned short*)p)[i]);
  }
};
template<> struct LD8<float> {
  static __device__ __forceinline__ short8 ld(const void* p, size_t i) {
    const float* fp = (const float*)p + i;
    float4 f0 = *(const float4*)fp;
    float4 f1 = *(const float4*)(fp + 4);
    short8 v;
    v[0]=(short)f2bfbits(f0.x); v[1]=(short)f2bfbits(f0.y);
    v[2]=(short)f2bfbits(f0.z); v[3]=(short)f2bfbits(f0.w);
    v[4]=(short)f2bfbits(f1.x); v[5]=(short)f2bfbits(f1.y);
    v[6]=(short)f2bfbits(f1.z); v[7]=(short)f2bfbits(f1.w);
    return v;
  }
  static __device__ __forceinline__ float lds(const void* p, size_t i) {
    return ((const float*)p)[i];
  }
};

// ---- dtype detect: low u16 of each u32 word of x ----
__global__ void detect_k(const unsigned int* __restrict__ x, int* __restrict__ flag) {
  int tid = threadIdx.x;
  int cnt = 0;
  for (int i = tid; i < 256; i += 64) {
    float a = fabsf(bf2f((unsigned short)(x[i] & 0xffffu)));
    if (a > 1e-3f && a < 10.f) cnt++;
  }
  for (int off = 32; off >= 1; off >>= 1) cnt += __shfl_xor(cnt, off);
  if (tid == 0) *flag = (cnt >= 128) ? 1 : 0;
}

// ---- unified MFMA GEMM: C = epi(A @ W^T + bias) ----
// Tile: 128 x BN (BN=128 or 64), BK=32, 4 waves, 16x16x32 bf16 MFMA.
// Dynamic LDS; blockIdx.z = K-split index; partial stored at z*csplit.
// mode 0: fp32 store; 1: +bias, silu, bf16 store; 3: plain bf16 store.
template<typename TA, typename TW, int BN>
__device__ __forceinline__ void mfma_body(
    const void* __restrict__ Av, const void* __restrict__ Wv,
    const void* __restrict__ biasv, void* __restrict__ Cv,
    int K, int lda, int ldb, int ldc, int mode, size_t csplit)
{
  extern __shared__ unsigned short smem[];
  unsigned short* As = smem;            // 128*40
  unsigned short* Bs = smem + 128*40;   // BN*40
  constexpr int MI = (BN == 128) ? 4 : 2;
  const int tid = threadIdx.x;
  const int m0 = blockIdx.x * 128;
  const int n0 = blockIdx.y * BN;
  const int kbase = blockIdx.z * K;
  const int lane = tid & 63;
  const int wv = tid >> 6;
  const int wm = (BN == 128) ? (wv >> 1) * 64 : wv * 32;
  const int wn = (BN == 128) ? (wv & 1) * 64 : 0;
  const int lr = lane & 15, lg = lane >> 4;

  f32x4 acc[MI][4];
  #pragma unroll
  for (int i = 0; i < MI; ++i)
    #pragma unroll
    for (int j = 0; j < 4; ++j) acc[i][j] = (f32x4){0.f, 0.f, 0.f, 0.f};

  for (int k0 = 0; k0 < K; k0 += 32) {
    short8 ra[2], rb[BN/64];
    #pragma unroll
    for (int r = 0; r < 2; ++r) {
      int chunk = tid + r*256;
      int row = chunk >> 2, sub = (chunk & 3) * 8;
      ra[r] = LD8<TA>::ld(Av, (size_t)(m0 + row)*lda + kbase + k0 + sub);
    }
    #pragma unroll
    for (int r = 0; r < BN/64; ++r) {
      int chunk = tid + r*256;
      int row = chunk >> 2, sub = (chunk & 3) * 8;
      rb[r] = LD8<TW>::ld(Wv, (size_t)(n0 + row)*ldb + kbase + k0 + sub);
    }
    __syncthreads();
    #pragma unroll
    for (int r = 0; r < 2; ++r) {
      int chunk = tid + r*256;
      int row = chunk >> 2, sub = (chunk & 3) * 8;
      *(short8*)&As[row*40 + sub] = ra[r];
    }
    #pragma unroll
    for (int r = 0; r < BN/64; ++r) {
      int chunk = tid + r*256;
      int row = chunk >> 2, sub = (chunk & 3) * 8;
      *(short8*)&Bs[row*40 + sub] = rb[r];
    }
    __syncthreads();
    short8 af[MI], bfr[4];
    #pragma unroll
    for (int i = 0; i < MI; ++i)
      af[i] = *(const short8*)&As[(wm + i*16 + lr)*40 + lg*8];
    #pragma unroll
    for (int j = 0; j < 4; ++j)
      bfr[j] = *(const short8*)&Bs[(wn + j*16 + lr)*40 + lg*8];
    #pragma unroll
    for (int i = 0; i < MI; ++i)
      #pragma unroll
      for (int j = 0; j < 4; ++j)
        acc[i][j] = __builtin_amdgcn_mfma_f32_16x16x32_bf16(af[i], bfr[j], acc[i][j], 0, 0, 0);
  }

  // C/D layout: col=lane&15, row=(lane>>4)*4+reg  [m89/m91 verified]
  size_t cz = (size_t)blockIdx.z * csplit;
  #pragma unroll
  for (int j = 0; j < 4; ++j) {
    int gn = n0 + wn + j*16 + lr;
    float bv = (mode == 1) ? LD8<TW>::lds(biasv, gn) : 0.f;
    #pragma unroll
    for (int i = 0; i < MI; ++i) {
      #pragma unroll
      for (int r = 0; r < 4; ++r) {
        int gm = m0 + wm + i*16 + lg*4 + r;
        float v = acc[i][j][r];
        if (mode == 1) {
          v += bv; v = v * sigmoidf_(v);
          ((unsigned short*)Cv)[cz + (size_t)gm*ldc + gn] = f2bfbits(v);
        } else if (mode == 3) {
          ((unsigned short*)Cv)[cz + (size_t)gm*ldc + gn] = f2bfbits(v);
        } else {
          ((float*)Cv)[cz + (size_t)gm*ldc + gn] = v;
        }
      }
    }
  }
}

template<int BN>
__global__ __launch_bounds__(256) void gemm_ain_k(const void* A, const void* W,
    const void* bias, void* C, int K, int lda, int ldb, int ldc, int mode,
    size_t csplit, const int* __restrict__ flag)
{
  if (*flag) mfma_body<unsigned short, unsigned short, BN>(A, W, bias, C, K, lda, ldb, ldc, mode, csplit);
  else       mfma_body<float, float, BN>(A, W, bias, C, K, lda, ldb, ldc, mode, csplit);
}
template<int BN>
__global__ __launch_bounds__(256) void gemm_a16_k(const void* A, const void* W,
    const void* bias, void* C, int K, int lda, int ldb, int ldc, int mode,
    size_t csplit, const int* __restrict__ flag)
{
  if (*flag) mfma_body<unsigned short, unsigned short, BN>(A, W, bias, C, K, lda, ldb, ldc, mode, csplit);
  else       mfma_body<unsigned short, float, BN>(A, W, bias, C, K, lda, ldb, ldc, mode, csplit);
}

// ---- delta GEMM: delta = softplus((xd0+xd1)[:, :32] @ W_dt^T + b_dt) -> bf16
// Single K-iteration (K=32) MFMA GEMM; sums split-K xdbl partials in A staging.
// grid (ML/128, DI/128). ----
__global__ __launch_bounds__(256) void dt_gemm_k(
    const float* __restrict__ xd, const void* __restrict__ W_dt,
    const void* __restrict__ b_dt, unsigned short* __restrict__ delta,
    const int* __restrict__ flag)
{
  __shared__ unsigned short As[128*40];
  __shared__ unsigned short Bs[128*40];
  const int tid = threadIdx.x;
  const int m0 = blockIdx.x * 128;
  const int n0 = blockIdx.y * 128;
  const int fl = *flag;
  const int row = tid >> 1, half = (tid & 1) * 16;
  {  // stage A: (p0+p1)[m0+row][half..half+16) -> bf16
    size_t g = (size_t)(m0 + row)*64 + half;
    const float* p0 = xd + g;
    const float* p1 = xd + (size_t)ML*64 + g;
    short8 v0, v1;
    #pragma unroll
    for (int q = 0; q < 8; q += 4) {
      float4 a4 = *(const float4*)(p0 + q);
      float4 b4 = *(const float4*)(p1 + q);
      v0[q+0] = (short)f2bfbits(a4.x + b4.x);
      v0[q+1] = (short)f2bfbits(a4.y + b4.y);
      v0[q+2] = (short)f2bfbits(a4.z + b4.z);
      v0[q+3] = (short)f2bfbits(a4.w + b4.w);
    }
    #pragma unroll
    for (int q = 0; q < 8; q += 4) {
      float4 a4 = *(const float4*)(p0 + 8 + q);
      float4 b4 = *(const float4*)(p1 + 8 + q);
      v1[q+0] = (short)f2bfbits(a4.x + b4.x);
      v1[q+1] = (short)f2bfbits(a4.y + b4.y);
      v1[q+2] = (short)f2bfbits(a4.z + b4.z);
      v1[q+3] = (short)f2bfbits(a4.w + b4.w);
    }
    *(short8*)&As[row*40 + half] = v0;
    *(short8*)&As[row*40 + half + 8] = v1;
  }
  {  // stage B: W_dt[n0+row][half..half+16) (DTR=32 cols per row)
    *(short8*)&Bs[row*40 + half]     = fl ? LD8<unsigned short>::ld(W_dt, (size_t)(n0+row)*DTR + half)
                                          : LD8<float>::ld(W_dt, (size_t)(n0+row)*DTR + half);
    *(short8*)&Bs[row*40 + half + 8] = fl ? LD8<unsigned short>::ld(W_dt, (size_t)(n0+row)*DTR + half + 8)
                                          : LD8<float>::ld(W_dt, (size_t)(n0+row)*DTR + half + 8);
  }
  __syncthreads();
  const int lane = tid & 63;
  const int wv = tid >> 6;
  const int wm = (wv >> 1) * 64, wn = (wv & 1) * 64;
  const int lr = lane & 15, lg = lane >> 4;
  f32x4 acc[4][4];
  #pragma unroll
  for (int i = 0; i < 4; ++i)
    #pragma unroll
    for (int j = 0; j < 4; ++j) acc[i][j] = (f32x4){0.f, 0.f, 0.f, 0.f};
  short8 af[4], bfr[4];
  #pragma unroll
  for (int i = 0; i < 4; ++i)
    af[i] = *(const short8*)&As[(wm + i*16 + lr)*40 + lg*8];
  #pragma unroll
  for (int j = 0; j < 4; ++j)
    bfr[j] = *(const short8*)&Bs[(wn + j*16 + lr)*40 + lg*8];
  #pragma unroll
  for (int i = 0; i < 4; ++i)
    #pragma unroll
    for (int j = 0; j < 4; ++j)
      acc[i][j] = __builtin_amdgcn_mfma_f32_16x16x32_bf16(af[i], bfr[j], acc[i][j], 0, 0, 0);
  #pragma unroll
  for (int j = 0; j < 4; ++j) {
    int gn = n0 + wn + j*16 + lr;
    float bv = ldf(b_dt, gn, fl);
    #pragma unroll
    for (int i = 0; i < 4; ++i) {
      #pragma unroll
      for (int r = 0; r < 4; ++r) {
        int gm = m0 + wm + i*16 + lg*4 + r;
        float v = acc[i][j][r] + bv;
        v = (v > 20.f) ? v : __logf(1.f + __expf(v));
        delta[(size_t)gm*DI + gn] = f2bfbits(v);
      }
    }
  }
}

// ---- z (gate) at last token; grid (16 b, 4 jchunk); vectorized W loads ----
__global__ __launch_bounds__(256) void zlast_k(const unsigned short* __restrict__ embed,
    const void* __restrict__ W_in, float* __restrict__ z_last, const int* __restrict__ flag)
{
  int b = blockIdx.x;
  int j = blockIdx.y * 256 + threadIdx.x;
  __shared__ float e[DM];
  for (int i = threadIdx.x; i < DM; i += 256)
    e[i] = bf2f(embed[(size_t)(b*L_ + L_-1)*DM + i]);
  __syncthreads();
  int fl = *flag;
  float acc = 0.f;
  if (fl) {
    const unsigned short* w = (const unsigned short*)W_in + (size_t)(DI + j)*DM;
    for (int k = 0; k < DM; k += 8) {
      short8 v = *(const short8*)&w[k];
      acc += e[k+0]*bf2f((unsigned short)v[0]) + e[k+1]*bf2f((unsigned short)v[1])
           + e[k+2]*bf2f((unsigned short)v[2]) + e[k+3]*bf2f((unsigned short)v[3])
           + e[k+4]*bf2f((unsigned short)v[4]) + e[k+5]*bf2f((unsigned short)v[5])
           + e[k+6]*bf2f((unsigned short)v[6]) + e[k+7]*bf2f((unsigned short)v[7]);
    }
  } else {
    const float* w = (const float*)W_in + (size_t)(DI + j)*DM;
    for (int k = 0; k < DM; k += 4) {
      float4 v = *(const float4*)&w[k];
      acc += e[k]*v.x + e[k+1]*v.y + e[k+2]*v.z + e[k+3]*v.w;
    }
  }
  z_last[b*DI + j] = acc;
}

// ---- causal depthwise conv + silu: xu bf16 -> u bf16 ----
__global__ __launch_bounds__(256) void conv_k(const unsigned short* __restrict__ xu,
    const void* __restrict__ conv_w, const void* __restrict__ conv_b,
    unsigned short* __restrict__ u, const int* __restrict__ flag)
{
  int bi = blockIdx.x;                    // 1024 blocks = b(16) x tc(16) x dchunk(4)
  int d  = (bi & 3)*256 + threadIdx.x;
  int tc = (bi >> 2) & 15;
  int b  = bi >> 6;
  int fl = *flag;
  float w0 = ldf(conv_w, (size_t)d*4 + 0, fl);
  float w1 = ldf(conv_w, (size_t)d*4 + 1, fl);
  float w2 = ldf(conv_w, (size_t)d*4 + 2, fl);
  float w3 = ldf(conv_w, (size_t)d*4 + 3, fl);
  float bias = ldf(conv_b, d, fl);
  int t0 = tc*64;
  const unsigned short* base = xu + (size_t)b*L_*DI + d;
  unsigned short* ubase = u + (size_t)b*L_*DI + d;
  float xm3 = (t0-3 >= 0) ? bf2f(base[(size_t)(t0-3)*DI]) : 0.f;
  float xm2 = (t0-2 >= 0) ? bf2f(base[(size_t)(t0-2)*DI]) : 0.f;
  float xm1 = (t0-1 >= 0) ? bf2f(base[(size_t)(t0-1)*DI]) : 0.f;
  for (int t = t0; t < t0+64; ++t) {
    float cur = bf2f(base[(size_t)t*DI]);
    float v = w0*xm3 + w1*xm2 + w2*xm1 + w3*cur + bias;
    ubase[(size_t)t*DI] = f2bfbits(v * sigmoidf_(v));
    xm3 = xm2; xm2 = xm1; xm1 = cur;
  }
}

// ---- scan v4: delta from memory (bf16); thread = 1 d, 16 n in registers.
// grid (16 b, 4 dchunk, NSEG); LDS = B only (4 KB). Coalesced (P,S) layout
// [seg][b][n][d]: h_full = P*h_in + S, P = exp(a_n * sum dt). ----
__global__ __launch_bounds__(256) void scan4_k(
    const unsigned short* __restrict__ delta, const unsigned short* __restrict__ u,
    const float* __restrict__ xd, const void* __restrict__ A_log,
    float2* __restrict__ ps, const int* __restrict__ flag)
{
  const int b = blockIdx.x;
  const int d0 = blockIdx.y * 256;
  const int seg = blockIdx.z;
  const int t0 = seg * SEGT;
  const int tid = threadIdx.x;
  const int d = d0 + tid;
  const int fl = *flag;
  __shared__ float sB[SEGT*16];
  #pragma unroll
  for (int i = 0; i < SEGT*16/256; ++i) {
    int idx = tid + i*256;
    int row = idx >> 4, n = idx & 15;
    size_t g = (size_t)(b*L_ + t0 + row)*64 + 32 + n;
    sB[idx] = xd[g] + xd[(size_t)ML*64 + g];
  }
  float a[16], h[16];
  #pragma unroll
  for (int n = 0; n < 16; ++n) {
    a[n] = -__expf(ldf(A_log, (size_t)d*NST + n, fl));
    h[n] = 0.f;
  }
  float sdt = 0.f;
  const unsigned short* dp = delta + (size_t)(b*L_ + t0)*DI + d;
  const unsigned short* up = u + (size_t)(b*L_ + t0)*DI + d;
  __syncthreads();
  unsigned short nd = dp[0], nu = up[0];
  for (int t = 0; t < SEGT; ++t) {
    float dt = bf2f(nd), ut = bf2f(nu);
    if (t < SEGT-1) { nd = dp[(size_t)(t+1)*DI]; nu = up[(size_t)(t+1)*DI]; }
    float g = dt * ut;
    sdt += dt;
    const float* Br = &sB[t*16];
    #pragma unroll
    for (int n = 0; n < 16; ++n)
      h[n] = __expf(dt*a[n])*h[n] + g*Br[n];
  }
  #pragma unroll
  for (int n = 0; n < 16; ++n) {
    float P = __expf(a[n]*sdt);
    ps[(((size_t)seg*16 + b)*16 + n)*DI + d] = make_float2(P, h[n]);
  }
}

// ---- fold segments + C-dot -> 4 y-partials (summed in head_k).
// grid (16 b, 4 dchunk, 4 nchunk); coalesced ps reads. ----
__global__ __launch_bounds__(256) void combine4_k(const float2* __restrict__ ps,
    const float* __restrict__ xd, float* __restrict__ ypart)
{
  int b = blockIdx.x;
  int d = blockIdx.y * 256 + threadIdx.x;
  int n0 = blockIdx.z * 4;
  float h[4] = {0.f, 0.f, 0.f, 0.f};
  for (int s = 0; s < NSEG; ++s) {
    #pragma unroll
    for (int q = 0; q < 4; ++q) {
      float2 v = ps[(((size_t)s*16 + b)*16 + n0 + q)*DI + d];
      h[q] = v.x*h[q] + v.y;
    }
  }
  float y = 0.f;
  #pragma unroll
  for (int q = 0; q < 4; ++q) {
    size_t gl = (size_t)(b*L_ + L_-1)*64 + 48 + n0 + q;
    float cn = xd[gl] + xd[(size_t)ML*64 + gl];
    y += h[q]*cn;
  }
  ypart[((size_t)blockIdx.z*16 + b)*DI + d] = y;
}

// ---- last-token epilogue: y*silu(z) -> W_out -> layernorm -> silu -> 17 heads ----
__global__ __launch_bounds__(512) void head_k(const float* __restrict__ ypart,
    const unsigned short* __restrict__ u, const float* __restrict__ z_last,
    const void* __restrict__ Dskip, const void* __restrict__ W_out,
    const void* __restrict__ W_critic, const void* __restrict__ b_critic,
    const void* __restrict__ W_amean, const void* __restrict__ b_amean,
    const void* __restrict__ W_astd, const void* __restrict__ b_astd,
    void* __restrict__ out, const int* __restrict__ flag)
{
  __shared__ float yz[DI];
  __shared__ float nb[DM];
  __shared__ float w1[8], w2[8];
  const int fl = *flag;
  int b = blockIdx.x;
  int tid = threadIdx.x;
  for (int i = tid; i < DI; i += 512) {
    float ys = ypart[(size_t)b*DI + i] + ypart[(size_t)(16+b)*DI + i]
             + ypart[(size_t)(32+b)*DI + i] + ypart[(size_t)(48+b)*DI + i]
             + bf2f(u[(size_t)(b*L_ + L_-1)*DI + i]) * ldf(Dskip, i, fl);
    float z = z_last[b*DI + i];
    yz[i] = ys * (z * sigmoidf_(z));
  }
  __syncthreads();
  float m = 0.f;
  if (fl) {
    const unsigned short* w = (const unsigned short*)W_out + (size_t)tid*DI;
    for (int k = 0; k < DI; k += 8) {
      short8 v = *(const short8*)&w[k];
      m += yz[k+0]*bf2f((unsigned short)v[0]) + yz[k+1]*bf2f((unsigned short)v[1])
         + yz[k+2]*bf2f((unsigned short)v[2]) + yz[k+3]*bf2f((unsigned short)v[3])
         + yz[k+4]*bf2f((unsigned short)v[4]) + yz[k+5]*bf2f((unsigned short)v[5])
         + yz[k+6]*bf2f((unsigned short)v[6]) + yz[k+7]*bf2f((unsigned short)v[7]);
    }
  } else {
    const float* w = (const float*)W_out + (size_t)tid*DI;
    for (int k = 0; k < DI; k += 4) {
      float4 v = *(const float4*)&w[k];
      m += yz[k]*v.x + yz[k+1]*v.y + yz[k+2]*v.z + yz[k+3]*v.w;
    }
  }
  float s1 = m, s2 = m*m;
  for (int off = 32; off >= 1; off >>= 1) { s1 += __shfl_xor(s1, off); s2 += __shfl_xor(s2, off); }
  int wid = tid >> 6, lane = tid & 63;
  if (lane == 0) { w1[wid] = s1; w2[wid] = s2; }
  __syncthreads();
  float t1 = 0.f, t2 = 0.f;
  for (int i = 0; i < 8; ++i) { t1 += w1[i]; t2 += w2[i]; }
  float mu  = t1 * (1.f/DM);
  float var = t2 * (1.f/DM) - mu*mu;
  float v = (m - mu) * rsqrtf(var + 1e-5f);
  nb[tid] = v * sigmoidf_(v);
  __syncthreads();
  for (int o = wid; o < 17; o += 8) {
    const void* w; size_t woff; float bias;
    if (o < 8)       { w = W_amean; woff = (size_t)o*DM;     bias = ldf(b_amean, o, fl); }
    else if (o < 16) { w = W_astd;  woff = (size_t)(o-8)*DM; bias = ldf(b_astd, o-8, fl); }
    else             { w = W_critic; woff = 0;               bias = ldf(b_critic, 0, fl); }
    float p = 0.f;
    for (int j = lane; j < DM; j += 64) p += nb[j] * ldf(w, woff + j, fl);
    for (int off = 32; off >= 1; off >>= 1) p += __shfl_xor(p, off);
    if (lane == 0) {
      float r = p + bias;
      int idx; float val;
      if (o < 8)       { idx = b*8 + o;           val = r; }
      else if (o < 16) { float ls = fminf(1.f, fmaxf(-1.f, r));
                         idx = 128 + b*8 + (o-8); val = expf(ls); }
      else             { idx = 256 + b;           val = r; }
      if (fl) ((bf16*)out)[idx] = __float2bfloat16(val);
      else    ((float*)out)[idx] = val;
    }
  }
}

extern "C" void kernel_launch(void* const* d_in, const int* in_sizes, int n_in,
                              void* d_out, int out_size, void* d_ws, size_t ws_size,
                              hipStream_t stream)
{
  const void* x        = d_in[0];
  const void* W_emb    = d_in[1];
  const void* b_emb    = d_in[2];
  const void* W_in     = d_in[3];
  const void* conv_w   = d_in[4];
  const void* conv_b   = d_in[5];
  const void* W_xproj  = d_in[6];
  const void* W_dt     = d_in[7];
  const void* b_dt     = d_in[8];
  const void* A_log    = d_in[9];
  const void* Dskip    = d_in[10];
  const void* W_out    = d_in[11];
  const void* W_critic = d_in[12];
  const void* b_critic = d_in[13];
  const void* W_amean  = d_in[14];
  const void* b_amean  = d_in[15];
  const void* W_astd   = d_in[16];
  const void* b_astd   = d_in[17];

  // workspace: embed 16 + xu 32 + u 32 + delta 32 + xdbl2 8 + ps 33.5 + small ~= 154 MB
  char* ws = (char*)d_ws;
  unsigned short* embed_bf = (unsigned short*)ws; ws += (size_t)ML*DM*2;
  unsigned short* xu_b  = (unsigned short*)ws; ws += (size_t)ML*DI*2;
  unsigned short* u_b   = (unsigned short*)ws; ws += (size_t)ML*DI*2;
  unsigned short* dlt_b = (unsigned short*)ws; ws += (size_t)ML*DI*2;
  float* xdbl2 = (float*)ws; ws += (size_t)2*ML*64*4;
  float2* psbuf = (float2*)ws; ws += (size_t)NSEG*B_*NST*DI*8;
  float* ypart = (float*)ws; ws += (size_t)4*B_*DI*4;
  float* zlast = (float*)ws; ws += (size_t)B_*DI*4;
  int*   flag  = (int*)ws;   ws += 64;

  // 0. detect input dtype (bf16 vs fp32)
  detect_k<<<1, 64, 0, stream>>>((const unsigned int*)x, flag);
  // 1. embed = silu(x @ W_emb^T + b_emb) -> bf16   (M=16384, N=512, K=32)
  gemm_ain_k<128><<<dim3(ML/128, DM/128), 256, 256*40*2, stream>>>(
      x, W_emb, b_emb, embed_bf, 32, 32, 32, DM, 1, 0, flag);
  // 2. xu = embed @ W_in[:DI]^T -> bf16   (M=16384, N=1024, K=512)
  gemm_a16_k<128><<<dim3(ML/128, DI/128), 256, 256*40*2, stream>>>(
      embed_bf, W_in, nullptr, xu_b, DM, DM, DM, DI, 3, 0, flag);
  // 2b. z at last token only
  zlast_k<<<dim3(16, 4), 256, 0, stream>>>(embed_bf, W_in, zlast, flag);
  // 3. u = silu(causal depthwise conv(xu)) -> bf16
  conv_k<<<1024, 256, 0, stream>>>(xu_b, conv_w, conv_b, u_b, flag);
  // 4. x_dbl = u @ W_xproj^T, split-K=2 -> two fp32 partials
  gemm_a16_k<64><<<dim3(ML/128, 1, 2), 256, 192*40*2, stream>>>(
      u_b, W_xproj, nullptr, xdbl2, 512, DI, DI, 64, 0, (size_t)ML*64, flag);
  // 5. delta = softplus(xdbl[:, :32] @ W_dt^T + b_dt) -> bf16  (MFMA, K=32)
  dt_gemm_k<<<dim3(ML/128, DI/128), 256, 0, stream>>>(
      xdbl2, W_dt, b_dt, dlt_b, flag);
  // 6. segmented scan (dt from memory) -> per-segment (P,S), coalesced layout
  scan4_k<<<dim3(B_, 4, NSEG), 256, 0, stream>>>(
      dlt_b, u_b, xdbl2, A_log, psbuf, flag);
  // 6b. fold segments + C-dot -> 4 y-partials
  combine4_k<<<dim3(B_, 4, 4), 256, 0, stream>>>(psbuf, xdbl2, ypart);
  // 7. gate, out-proj, layernorm, silu, heads
  head_k<<<16, 512, 0, stream>>>(ypart, u_b, zlast, Dskip, W_out, W_critic, b_critic,
                                 W_amean, b_amean, W_astd, b_astd, (void*)d_out, flag);
}

// Round 11
// 347.238 us; speedup vs baseline: 1.9262x; 1.0152x over previous
//
#include <hip/hip_runtime.h>
#include <hip/hip_bf16.h>
#include <math.h>

// Problem constants (MambaAgent reference)
#define B_   16
#define L_   1024
#define DM   512          // D_MODEL
#define DI   1024         // D_INNER
#define NST  16           // D_STATE
#define DTR  32           // DT_RANK
#define ML   (B_*L_)      // 16384 rows
#define SEGT 64           // t-steps per scan segment
#define NSEG (L_/SEGT)    // 16

typedef __hip_bfloat16 bf16;
typedef __attribute__((ext_vector_type(8))) short short8;
typedef __attribute__((ext_vector_type(4))) float f32x4;

__device__ __forceinline__ float bf2f(unsigned short u) {
  union { unsigned int i; float f; } v; v.i = ((unsigned int)u) << 16; return v.f;
}
__device__ __forceinline__ unsigned short f2bfbits(float f) {
  bf16 h = __float2bfloat16(f);
  return *(unsigned short*)&h;
}
__device__ __forceinline__ float sigmoidf_(float v) { return 1.f/(1.f+__expf(-v)); }
// runtime-dtype scalar load (fl=1: bf16, fl=0: fp32)
__device__ __forceinline__ float ldf(const void* p, size_t i, int fl) {
  return fl ? bf2f(((const unsigned short*)p)[i]) : ((const float*)p)[i];
}

// ---- 8-element bf16-fragment loads: direct (ushort) or fp32->bf16 convert ----
template<typename T> struct LD8;
template<> struct LD8<unsigned short> {
  static __device__ __forceinline__ short8 ld(const void* p, size_t i) {
    return *(const short8*)((const unsigned short*)p + i);
  }
  static __device__ __forceinline__ float lds(const void* p, size_t i) {
    return bf2f(((const unsigned short*)p)[i]);
  }
};
template<> struct LD8<float> {
  static __device__ __forceinline__ short8 ld(const void* p, size_t i) {
    const float* fp = (const float*)p + i;
    float4 f0 = *(const float4*)fp;
    float4 f1 = *(const float4*)(fp + 4);
    short8 v;
    v[0]=(short)f2bfbits(f0.x); v[1]=(short)f2bfbits(f0.y);
    v[2]=(short)f2bfbits(f0.z); v[3]=(short)f2bfbits(f0.w);
    v[4]=(short)f2bfbits(f1.x); v[5]=(short)f2bfbits(f1.y);
    v[6]=(short)f2bfbits(f1.z); v[7]=(short)f2bfbits(f1.w);
    return v;
  }
  static __device__ __forceinline__ float lds(const void* p, size_t i) {
    return ((const float*)p)[i];
  }
};

// ---- dtype detect: low u16 of each u32 word of x ----
__global__ void detect_k(const unsigned int* __restrict__ x, int* __restrict__ flag) {
  int tid = threadIdx.x;
  int cnt = 0;
  for (int i = tid; i < 256; i += 64) {
    float a = fabsf(bf2f((unsigned short)(x[i] & 0xffffu)));
    if (a > 1e-3f && a < 10.f) cnt++;
  }
  for (int off = 32; off >= 1; off >>= 1) cnt += __shfl_xor(cnt, off);
  if (tid == 0) *flag = (cnt >= 128) ? 1 : 0;
}

// ---- unified MFMA GEMM: C = epi(A @ W^T + bias) ----
// Tile: 128 x BN (BN=128 or 64), BK=32, 4 waves, 16x16x32 bf16 MFMA.
// Dynamic LDS; blockIdx.z = K-split index; partial stored at z*csplit.
// mode 0: fp32 store; 1: +bias, silu, bf16 store; 3: plain bf16 store.
template<typename TA, typename TW, int BN>
__device__ __forceinline__ void mfma_body(
    const void* __restrict__ Av, const void* __restrict__ Wv,
    const void* __restrict__ biasv, void* __restrict__ Cv,
    int K, int lda, int ldb, int ldc, int mode, size_t csplit)
{
  extern __shared__ unsigned short smem[];
  unsigned short* As = smem;            // 128*40
  unsigned short* Bs = smem + 128*40;   // BN*40
  constexpr int MI = (BN == 128) ? 4 : 2;
  const int tid = threadIdx.x;
  const int m0 = blockIdx.x * 128;
  const int n0 = blockIdx.y * BN;
  const int kbase = blockIdx.z * K;
  const int lane = tid & 63;
  const int wv = tid >> 6;
  const int wm = (BN == 128) ? (wv >> 1) * 64 : wv * 32;
  const int wn = (BN == 128) ? (wv & 1) * 64 : 0;
  const int lr = lane & 15, lg = lane >> 4;

  f32x4 acc[MI][4];
  #pragma unroll
  for (int i = 0; i < MI; ++i)
    #pragma unroll
    for (int j = 0; j < 4; ++j) acc[i][j] = (f32x4){0.f, 0.f, 0.f, 0.f};

  for (int k0 = 0; k0 < K; k0 += 32) {
    short8 ra[2], rb[BN/64];
    #pragma unroll
    for (int r = 0; r < 2; ++r) {
      int chunk = tid + r*256;
      int row = chunk >> 2, sub = (chunk & 3) * 8;
      ra[r] = LD8<TA>::ld(Av, (size_t)(m0 + row)*lda + kbase + k0 + sub);
    }
    #pragma unroll
    for (int r = 0; r < BN/64; ++r) {
      int chunk = tid + r*256;
      int row = chunk >> 2, sub = (chunk & 3) * 8;
      rb[r] = LD8<TW>::ld(Wv, (size_t)(n0 + row)*ldb + kbase + k0 + sub);
    }
    __syncthreads();
    #pragma unroll
    for (int r = 0; r < 2; ++r) {
      int chunk = tid + r*256;
      int row = chunk >> 2, sub = (chunk & 3) * 8;
      *(short8*)&As[row*40 + sub] = ra[r];
    }
    #pragma unroll
    for (int r = 0; r < BN/64; ++r) {
      int chunk = tid + r*256;
      int row = chunk >> 2, sub = (chunk & 3) * 8;
      *(short8*)&Bs[row*40 + sub] = rb[r];
    }
    __syncthreads();
    short8 af[MI], bfr[4];
    #pragma unroll
    for (int i = 0; i < MI; ++i)
      af[i] = *(const short8*)&As[(wm + i*16 + lr)*40 + lg*8];
    #pragma unroll
    for (int j = 0; j < 4; ++j)
      bfr[j] = *(const short8*)&Bs[(wn + j*16 + lr)*40 + lg*8];
    #pragma unroll
    for (int i = 0; i < MI; ++i)
      #pragma unroll
      for (int j = 0; j < 4; ++j)
        acc[i][j] = __builtin_amdgcn_mfma_f32_16x16x32_bf16(af[i], bfr[j], acc[i][j], 0, 0, 0);
  }

  // C/D layout: col=lane&15, row=(lane>>4)*4+reg  [m89/m91 verified]
  size_t cz = (size_t)blockIdx.z * csplit;
  #pragma unroll
  for (int j = 0; j < 4; ++j) {
    int gn = n0 + wn + j*16 + lr;
    float bv = (mode == 1) ? LD8<TW>::lds(biasv, gn) : 0.f;
    #pragma unroll
    for (int i = 0; i < MI; ++i) {
      #pragma unroll
      for (int r = 0; r < 4; ++r) {
        int gm = m0 + wm + i*16 + lg*4 + r;
        float v = acc[i][j][r];
        if (mode == 1) {
          v += bv; v = v * sigmoidf_(v);
          ((unsigned short*)Cv)[cz + (size_t)gm*ldc + gn] = f2bfbits(v);
        } else if (mode == 3) {
          ((unsigned short*)Cv)[cz + (size_t)gm*ldc + gn] = f2bfbits(v);
        } else {
          ((float*)Cv)[cz + (size_t)gm*ldc + gn] = v;
        }
      }
    }
  }
}

template<int BN>
__global__ __launch_bounds__(256) void gemm_ain_k(const void* A, const void* W,
    const void* bias, void* C, int K, int lda, int ldb, int ldc, int mode,
    size_t csplit, const int* __restrict__ flag)
{
  if (*flag) mfma_body<unsigned short, unsigned short, BN>(A, W, bias, C, K, lda, ldb, ldc, mode, csplit);
  else       mfma_body<float, float, BN>(A, W, bias, C, K, lda, ldb, ldc, mode, csplit);
}
template<int BN>
__global__ __launch_bounds__(256) void gemm_a16_k(const void* A, const void* W,
    const void* bias, void* C, int K, int lda, int ldb, int ldc, int mode,
    size_t csplit, const int* __restrict__ flag)
{
  if (*flag) mfma_body<unsigned short, unsigned short, BN>(A, W, bias, C, K, lda, ldb, ldc, mode, csplit);
  else       mfma_body<unsigned short, float, BN>(A, W, bias, C, K, lda, ldb, ldc, mode, csplit);
}

// ---- delta GEMM: delta = softplus((xd0+xd1)[:, :32] @ W_dt^T + b_dt) -> bf16
// Single K-iteration (K=32) MFMA GEMM; sums split-K xdbl partials in A staging. ----
__global__ __launch_bounds__(256) void dt_gemm_k(
    const float* __restrict__ xd, const void* __restrict__ W_dt,
    const void* __restrict__ b_dt, unsigned short* __restrict__ delta,
    const int* __restrict__ flag)
{
  __shared__ unsigned short As[128*40];
  __shared__ unsigned short Bs[128*40];
  const int tid = threadIdx.x;
  const int m0 = blockIdx.x * 128;
  const int n0 = blockIdx.y * 128;
  const int fl = *flag;
  const int row = tid >> 1, half = (tid & 1) * 16;
  {  // stage A: (p0+p1)[m0+row][half..half+16) -> bf16
    size_t g = (size_t)(m0 + row)*64 + half;
    const float* p0 = xd + g;
    const float* p1 = xd + (size_t)ML*64 + g;
    short8 v0, v1;
    #pragma unroll
    for (int q = 0; q < 8; q += 4) {
      float4 a4 = *(const float4*)(p0 + q);
      float4 b4 = *(const float4*)(p1 + q);
      v0[q+0] = (short)f2bfbits(a4.x + b4.x);
      v0[q+1] = (short)f2bfbits(a4.y + b4.y);
      v0[q+2] = (short)f2bfbits(a4.z + b4.z);
      v0[q+3] = (short)f2bfbits(a4.w + b4.w);
    }
    #pragma unroll
    for (int q = 0; q < 8; q += 4) {
      float4 a4 = *(const float4*)(p0 + 8 + q);
      float4 b4 = *(const float4*)(p1 + 8 + q);
      v1[q+0] = (short)f2bfbits(a4.x + b4.x);
      v1[q+1] = (short)f2bfbits(a4.y + b4.y);
      v1[q+2] = (short)f2bfbits(a4.z + b4.z);
      v1[q+3] = (short)f2bfbits(a4.w + b4.w);
    }
    *(short8*)&As[row*40 + half] = v0;
    *(short8*)&As[row*40 + half + 8] = v1;
  }
  {  // stage B: W_dt[n0+row][half..half+16)
    *(short8*)&Bs[row*40 + half]     = fl ? LD8<unsigned short>::ld(W_dt, (size_t)(n0+row)*DTR + half)
                                          : LD8<float>::ld(W_dt, (size_t)(n0+row)*DTR + half);
    *(short8*)&Bs[row*40 + half + 8] = fl ? LD8<unsigned short>::ld(W_dt, (size_t)(n0+row)*DTR + half + 8)
                                          : LD8<float>::ld(W_dt, (size_t)(n0+row)*DTR + half + 8);
  }
  __syncthreads();
  const int lane = tid & 63;
  const int wv = tid >> 6;
  const int wm = (wv >> 1) * 64, wn = (wv & 1) * 64;
  const int lr = lane & 15, lg = lane >> 4;
  f32x4 acc[4][4];
  #pragma unroll
  for (int i = 0; i < 4; ++i)
    #pragma unroll
    for (int j = 0; j < 4; ++j) acc[i][j] = (f32x4){0.f, 0.f, 0.f, 0.f};
  short8 af[4], bfr[4];
  #pragma unroll
  for (int i = 0; i < 4; ++i)
    af[i] = *(const short8*)&As[(wm + i*16 + lr)*40 + lg*8];
  #pragma unroll
  for (int j = 0; j < 4; ++j)
    bfr[j] = *(const short8*)&Bs[(wn + j*16 + lr)*40 + lg*8];
  #pragma unroll
  for (int i = 0; i < 4; ++i)
    #pragma unroll
    for (int j = 0; j < 4; ++j)
      acc[i][j] = __builtin_amdgcn_mfma_f32_16x16x32_bf16(af[i], bfr[j], acc[i][j], 0, 0, 0);
  #pragma unroll
  for (int j = 0; j < 4; ++j) {
    int gn = n0 + wn + j*16 + lr;
    float bv = ldf(b_dt, gn, fl);
    #pragma unroll
    for (int i = 0; i < 4; ++i) {
      #pragma unroll
      for (int r = 0; r < 4; ++r) {
        int gm = m0 + wm + i*16 + lg*4 + r;
        float v = acc[i][j][r] + bv;
        v = (v > 20.f) ? v : __logf(1.f + __expf(v));
        delta[(size_t)gm*DI + gn] = f2bfbits(v);
      }
    }
  }
}

// ---- zlast v2: wave-per-row coalesced. grid (16 b, 16 jchunk of 64). ----
__global__ __launch_bounds__(256) void zlast2_k(const unsigned short* __restrict__ embed,
    const void* __restrict__ W_in, float* __restrict__ z_last, const int* __restrict__ flag)
{
  int b = blockIdx.x;
  int j0 = blockIdx.y * 64;
  int tid = threadIdx.x;
  __shared__ float e[DM];
  for (int i = tid; i < DM; i += 256)
    e[i] = bf2f(embed[(size_t)(b*L_ + L_-1)*DM + i]);
  __syncthreads();
  int fl = *flag;
  int wid = tid >> 6, lane = tid & 63;
  for (int jj = wid; jj < 64; jj += 4) {
    int j = j0 + jj;
    float p = 0.f;
    int k = lane * 8;                       // DM=512 = 64 lanes x 8
    if (fl) {
      const unsigned short* w = (const unsigned short*)W_in + (size_t)(DI + j)*DM + k;
      short8 v = *(const short8*)w;
      #pragma unroll
      for (int q = 0; q < 8; ++q) p += e[k+q]*bf2f((unsigned short)v[q]);
    } else {
      const float* w = (const float*)W_in + (size_t)(DI + j)*DM + k;
      float4 v0 = *(const float4*)w;
      float4 v1 = *(const float4*)(w + 4);
      p = e[k]*v0.x + e[k+1]*v0.y + e[k+2]*v0.z + e[k+3]*v0.w
        + e[k+4]*v1.x + e[k+5]*v1.y + e[k+6]*v1.z + e[k+7]*v1.w;
    }
    for (int off = 32; off >= 1; off >>= 1) p += __shfl_xor(p, off);
    if (lane == 0) z_last[b*DI + j] = p;
  }
}

// ---- causal depthwise conv + silu: xu bf16 -> u bf16 ----
__global__ __launch_bounds__(256) void conv_k(const unsigned short* __restrict__ xu,
    const void* __restrict__ conv_w, const void* __restrict__ conv_b,
    unsigned short* __restrict__ u, const int* __restrict__ flag)
{
  int bi = blockIdx.x;                    // 1024 blocks = b(16) x tc(16) x dchunk(4)
  int d  = (bi & 3)*256 + threadIdx.x;
  int tc = (bi >> 2) & 15;
  int b  = bi >> 6;
  int fl = *flag;
  float w0 = ldf(conv_w, (size_t)d*4 + 0, fl);
  float w1 = ldf(conv_w, (size_t)d*4 + 1, fl);
  float w2 = ldf(conv_w, (size_t)d*4 + 2, fl);
  float w3 = ldf(conv_w, (size_t)d*4 + 3, fl);
  float bias = ldf(conv_b, d, fl);
  int t0 = tc*64;
  const unsigned short* base = xu + (size_t)b*L_*DI + d;
  unsigned short* ubase = u + (size_t)b*L_*DI + d;
  float xm3 = (t0-3 >= 0) ? bf2f(base[(size_t)(t0-3)*DI]) : 0.f;
  float xm2 = (t0-2 >= 0) ? bf2f(base[(size_t)(t0-2)*DI]) : 0.f;
  float xm1 = (t0-1 >= 0) ? bf2f(base[(size_t)(t0-1)*DI]) : 0.f;
  for (int t = t0; t < t0+64; ++t) {
    float cur = bf2f(base[(size_t)t*DI]);
    float v = w0*xm3 + w1*xm2 + w2*xm1 + w3*cur + bias;
    ubase[(size_t)t*DI] = f2bfbits(v * sigmoidf_(v));
    xm3 = xm2; xm2 = xm1; xm1 = cur;
  }
}

// ---- scan v4: delta from memory (bf16); thread = 1 d, 16 n in registers. ----
__global__ __launch_bounds__(256) void scan4_k(
    const unsigned short* __restrict__ delta, const unsigned short* __restrict__ u,
    const float* __restrict__ xd, const void* __restrict__ A_log,
    float2* __restrict__ ps, const int* __restrict__ flag)
{
  const int b = blockIdx.x;
  const int d0 = blockIdx.y * 256;
  const int seg = blockIdx.z;
  const int t0 = seg * SEGT;
  const int tid = threadIdx.x;
  const int d = d0 + tid;
  const int fl = *flag;
  __shared__ float sB[SEGT*16];
  #pragma unroll
  for (int i = 0; i < SEGT*16/256; ++i) {
    int idx = tid + i*256;
    int row = idx >> 4, n = idx & 15;
    size_t g = (size_t)(b*L_ + t0 + row)*64 + 32 + n;
    sB[idx] = xd[g] + xd[(size_t)ML*64 + g];
  }
  float a[16], h[16];
  #pragma unroll
  for (int n = 0; n < 16; ++n) {
    a[n] = -__expf(ldf(A_log, (size_t)d*NST + n, fl));
    h[n] = 0.f;
  }
  float sdt = 0.f;
  const unsigned short* dp = delta + (size_t)(b*L_ + t0)*DI + d;
  const unsigned short* up = u + (size_t)(b*L_ + t0)*DI + d;
  __syncthreads();
  unsigned short nd = dp[0], nu = up[0];
  for (int t = 0; t < SEGT; ++t) {
    float dt = bf2f(nd), ut = bf2f(nu);
    if (t < SEGT-1) { nd = dp[(size_t)(t+1)*DI]; nu = up[(size_t)(t+1)*DI]; }
    float g = dt * ut;
    sdt += dt;
    const float* Br = &sB[t*16];
    #pragma unroll
    for (int n = 0; n < 16; ++n)
      h[n] = __expf(dt*a[n])*h[n] + g*Br[n];
  }
  #pragma unroll
  for (int n = 0; n < 16; ++n) {
    float P = __expf(a[n]*sdt);
    ps[(((size_t)seg*16 + b)*16 + n)*DI + d] = make_float2(P, h[n]);
  }
}

// ---- fold segments + C-dot -> 4 y-partials. grid (16 b, 4 dchunk, 4 nchunk). ----
__global__ __launch_bounds__(256) void combine4_k(const float2* __restrict__ ps,
    const float* __restrict__ xd, float* __restrict__ ypart)
{
  int b = blockIdx.x;
  int d = blockIdx.y * 256 + threadIdx.x;
  int n0 = blockIdx.z * 4;
  float h[4] = {0.f, 0.f, 0.f, 0.f};
  for (int s = 0; s < NSEG; ++s) {
    #pragma unroll
    for (int q = 0; q < 4; ++q) {
      float2 v = ps[(((size_t)s*16 + b)*16 + n0 + q)*DI + d];
      h[q] = v.x*h[q] + v.y;
    }
  }
  float y = 0.f;
  #pragma unroll
  for (int q = 0; q < 4; ++q) {
    size_t gl = (size_t)(b*L_ + L_-1)*64 + 48 + n0 + q;
    float cn = xd[gl] + xd[(size_t)ML*64 + gl];
    y += h[q]*cn;
  }
  ypart[((size_t)blockIdx.z*16 + b)*DI + d] = y;
}

// ---- mdot: m[b][row] = yz[b] . W_out[row]; wave-per-row coalesced.
// grid (16 b, 8 rowchunk of 64). yz built in LDS from ypart/u/Dskip/z_last. ----
__global__ __launch_bounds__(256) void mdot_k(const float* __restrict__ ypart,
    const unsigned short* __restrict__ u, const float* __restrict__ z_last,
    const void* __restrict__ Dskip, const void* __restrict__ W_out,
    float* __restrict__ m_out, const int* __restrict__ flag)
{
  int b = blockIdx.x;
  int r0 = blockIdx.y * 64;
  int tid = threadIdx.x;
  const int fl = *flag;
  __shared__ float yz[DI];
  for (int i = tid; i < DI; i += 256) {
    float ys = ypart[(size_t)b*DI + i] + ypart[(size_t)(16+b)*DI + i]
             + ypart[(size_t)(32+b)*DI + i] + ypart[(size_t)(48+b)*DI + i]
             + bf2f(u[(size_t)(b*L_ + L_-1)*DI + i]) * ldf(Dskip, i, fl);
    float z = z_last[b*DI + i];
    yz[i] = ys * (z * sigmoidf_(z));
  }
  __syncthreads();
  int wid = tid >> 6, lane = tid & 63;
  int k = lane * 8;                          // covers 512; second half at 512+k
  for (int rr = wid; rr < 64; rr += 4) {
    int row = r0 + rr;
    float p = 0.f;
    if (fl) {
      const unsigned short* w = (const unsigned short*)W_out + (size_t)row*DI;
      short8 v0 = *(const short8*)(w + k);
      short8 v1 = *(const short8*)(w + 512 + k);
      #pragma unroll
      for (int q = 0; q < 8; ++q)
        p += yz[k+q]*bf2f((unsigned short)v0[q]) + yz[512+k+q]*bf2f((unsigned short)v1[q]);
    } else {
      const float* w = (const float*)W_out + (size_t)row*DI;
      float4 a0 = *(const float4*)(w + k),      a1 = *(const float4*)(w + k + 4);
      float4 b0 = *(const float4*)(w + 512 + k), b1 = *(const float4*)(w + 512 + k + 4);
      p = yz[k]*a0.x + yz[k+1]*a0.y + yz[k+2]*a0.z + yz[k+3]*a0.w
        + yz[k+4]*a1.x + yz[k+5]*a1.y + yz[k+6]*a1.z + yz[k+7]*a1.w
        + yz[512+k]*b0.x + yz[512+k+1]*b0.y + yz[512+k+2]*b0.z + yz[512+k+3]*b0.w
        + yz[512+k+4]*b1.x + yz[512+k+5]*b1.y + yz[512+k+6]*b1.z + yz[512+k+7]*b1.w;
    }
    for (int off = 32; off >= 1; off >>= 1) p += __shfl_xor(p, off);
    if (lane == 0) m_out[b*DM + row] = p;
  }
}

// ---- head v2: layernorm(m) -> silu -> 17 head dots. 16 blocks x 512. ----
__global__ __launch_bounds__(512) void head2_k(const float* __restrict__ m_in,
    const void* __restrict__ W_critic, const void* __restrict__ b_critic,
    const void* __restrict__ W_amean, const void* __restrict__ b_amean,
    const void* __restrict__ W_astd, const void* __restrict__ b_astd,
    void* __restrict__ out, const int* __restrict__ flag)
{
  __shared__ float nb[DM];
  __shared__ float w1[8], w2[8];
  const int fl = *flag;
  int b = blockIdx.x;
  int tid = threadIdx.x;
  float m = m_in[b*DM + tid];
  float s1 = m, s2 = m*m;
  for (int off = 32; off >= 1; off >>= 1) { s1 += __shfl_xor(s1, off); s2 += __shfl_xor(s2, off); }
  int wid = tid >> 6, lane = tid & 63;
  if (lane == 0) { w1[wid] = s1; w2[wid] = s2; }
  __syncthreads();
  float t1 = 0.f, t2 = 0.f;
  for (int i = 0; i < 8; ++i) { t1 += w1[i]; t2 += w2[i]; }
  float mu  = t1 * (1.f/DM);
  float var = t2 * (1.f/DM) - mu*mu;
  float v = (m - mu) * rsqrtf(var + 1e-5f);
  nb[tid] = v * sigmoidf_(v);
  __syncthreads();
  for (int o = wid; o < 17; o += 8) {
    const void* w; size_t woff; float bias;
    if (o < 8)       { w = W_amean; woff = (size_t)o*DM;     bias = ldf(b_amean, o, fl); }
    else if (o < 16) { w = W_astd;  woff = (size_t)(o-8)*DM; bias = ldf(b_astd, o-8, fl); }
    else             { w = W_critic; woff = 0;               bias = ldf(b_critic, 0, fl); }
    float p = 0.f;
    for (int j = lane; j < DM; j += 64) p += nb[j] * ldf(w, woff + j, fl);
    for (int off = 32; off >= 1; off >>= 1) p += __shfl_xor(p, off);
    if (lane == 0) {
      float r = p + bias;
      int idx; float val;
      if (o < 8)       { idx = b*8 + o;           val = r; }
      else if (o < 16) { float ls = fminf(1.f, fmaxf(-1.f, r));
                         idx = 128 + b*8 + (o-8); val = expf(ls); }
      else             { idx = 256 + b;           val = r; }
      if (fl) ((bf16*)out)[idx] = __float2bfloat16(val);
      else    ((float*)out)[idx] = val;
    }
  }
}

extern "C" void kernel_launch(void* const* d_in, const int* in_sizes, int n_in,
                              void* d_out, int out_size, void* d_ws, size_t ws_size,
                              hipStream_t stream)
{
  const void* x        = d_in[0];
  const void* W_emb    = d_in[1];
  const void* b_emb    = d_in[2];
  const void* W_in     = d_in[3];
  const void* conv_w   = d_in[4];
  const void* conv_b   = d_in[5];
  const void* W_xproj  = d_in[6];
  const void* W_dt     = d_in[7];
  const void* b_dt     = d_in[8];
  const void* A_log    = d_in[9];
  const void* Dskip    = d_in[10];
  const void* W_out    = d_in[11];
  const void* W_critic = d_in[12];
  const void* b_critic = d_in[13];
  const void* W_amean  = d_in[14];
  const void* b_amean  = d_in[15];
  const void* W_astd   = d_in[16];
  const void* b_astd   = d_in[17];

  // workspace: embed 16 + xu 32 + u 32 + delta 32 + xdbl2 8 + ps 33.5 + small ~= 154 MB
  char* ws = (char*)d_ws;
  unsigned short* embed_bf = (unsigned short*)ws; ws += (size_t)ML*DM*2;
  unsigned short* xu_b  = (unsigned short*)ws; ws += (size_t)ML*DI*2;
  unsigned short* u_b   = (unsigned short*)ws; ws += (size_t)ML*DI*2;
  unsigned short* dlt_b = (unsigned short*)ws; ws += (size_t)ML*DI*2;
  float* xdbl2 = (float*)ws; ws += (size_t)2*ML*64*4;
  float2* psbuf = (float2*)ws; ws += (size_t)NSEG*B_*NST*DI*8;
  float* ypart = (float*)ws; ws += (size_t)4*B_*DI*4;
  float* zlast = (float*)ws; ws += (size_t)B_*DI*4;
  float* mbuf  = (float*)ws; ws += (size_t)B_*DM*4;
  int*   flag  = (int*)ws;   ws += 64;

  // 0. detect input dtype (bf16 vs fp32)
  detect_k<<<1, 64, 0, stream>>>((const unsigned int*)x, flag);
  // 1. embed = silu(x @ W_emb^T + b_emb) -> bf16   (M=16384, N=512, K=32)
  gemm_ain_k<128><<<dim3(ML/128, DM/128), 256, 256*40*2, stream>>>(
      x, W_emb, b_emb, embed_bf, 32, 32, 32, DM, 1, 0, flag);
  // 2. xu = embed @ W_in[:DI]^T -> bf16   (M=16384, N=1024, K=512)
  gemm_a16_k<128><<<dim3(ML/128, DI/128), 256, 256*40*2, stream>>>(
      embed_bf, W_in, nullptr, xu_b, DM, DM, DM, DI, 3, 0, flag);
  // 2b. z at last token only (wave-per-row coalesced)
  zlast2_k<<<dim3(16, 16), 256, 0, stream>>>(embed_bf, W_in, zlast, flag);
  // 3. u = silu(causal depthwise conv(xu)) -> bf16
  conv_k<<<1024, 256, 0, stream>>>(xu_b, conv_w, conv_b, u_b, flag);
  // 4. x_dbl = u @ W_xproj^T, split-K=2 -> two fp32 partials
  gemm_a16_k<64><<<dim3(ML/128, 1, 2), 256, 192*40*2, stream>>>(
      u_b, W_xproj, nullptr, xdbl2, 512, DI, DI, 64, 0, (size_t)ML*64, flag);
  // 5. delta = softplus(xdbl[:, :32] @ W_dt^T + b_dt) -> bf16  (MFMA, K=32)
  dt_gemm_k<<<dim3(ML/128, DI/128), 256, 0, stream>>>(
      xdbl2, W_dt, b_dt, dlt_b, flag);
  // 6. segmented scan (dt from memory) -> per-segment (P,S), coalesced layout
  scan4_k<<<dim3(B_, 4, NSEG), 256, 0, stream>>>(
      dlt_b, u_b, xdbl2, A_log, psbuf, flag);
  // 6b. fold segments + C-dot -> 4 y-partials
  combine4_k<<<dim3(B_, 4, 4), 256, 0, stream>>>(psbuf, xdbl2, ypart);
  // 7a. m = yz @ W_out^T (wave-per-row coalesced, 128 blocks)
  mdot_k<<<dim3(16, 8), 256, 0, stream>>>(ypart, u_b, zlast, Dskip, W_out, mbuf, flag);
  // 7b. layernorm + silu + 17 heads
  head2_k<<<16, 512, 0, stream>>>(mbuf, W_critic, b_critic,
                                  W_amean, b_amean, W_astd, b_astd, (void*)d_out, flag);
}

// Round 12
// 316.335 us; speedup vs baseline: 2.1144x; 1.0977x over previous
//
#include <hip/hip_runtime.h>
#include <hip/hip_bf16.h>
#include <math.h>

// Problem constants (MambaAgent reference)
#define B_   16
#define L_   1024
#define DM   512          // D_MODEL
#define DI   1024         // D_INNER
#define NST  16           // D_STATE
#define DTR  32           // DT_RANK
#define ML   (B_*L_)      // 16384 rows
#define SEGT 64           // t-steps per scan segment
#define NSEG (L_/SEGT)    // 16

typedef __hip_bfloat16 bf16;
typedef __attribute__((ext_vector_type(8))) short short8;
typedef __attribute__((ext_vector_type(4))) float f32x4;

__device__ __forceinline__ float bf2f(unsigned short u) {
  union { unsigned int i; float f; } v; v.i = ((unsigned int)u) << 16; return v.f;
}
__device__ __forceinline__ unsigned short f2bfbits(float f) {
  bf16 h = __float2bfloat16(f);
  return *(unsigned short*)&h;
}
__device__ __forceinline__ float sigmoidf_(float v) { return 1.f/(1.f+__expf(-v)); }
// runtime-dtype scalar load (fl=1: bf16, fl=0: fp32)
__device__ __forceinline__ float ldf(const void* p, size_t i, int fl) {
  return fl ? bf2f(((const unsigned short*)p)[i]) : ((const float*)p)[i];
}
// async global->LDS DMA, 16 B per lane; LDS dest = wave-uniform base + lane*16
__device__ __forceinline__ void gload16(const void* g, void* l) {
  __builtin_amdgcn_global_load_lds(
      (const __attribute__((address_space(1))) void*)g,
      (__attribute__((address_space(3))) void*)l, 16, 0, 0);
}

// ---- 8-element bf16-fragment loads: direct (ushort) or fp32->bf16 convert ----
template<typename T> struct LD8;
template<> struct LD8<unsigned short> {
  static __device__ __forceinline__ short8 ld(const void* p, size_t i) {
    return *(const short8*)((const unsigned short*)p + i);
  }
  static __device__ __forceinline__ float lds(const void* p, size_t i) {
    return bf2f(((const unsigned short*)p)[i]);
  }
};
template<> struct LD8<float> {
  static __device__ __forceinline__ short8 ld(const void* p, size_t i) {
    const float* fp = (const float*)p + i;
    float4 f0 = *(const float4*)fp;
    float4 f1 = *(const float4*)(fp + 4);
    short8 v;
    v[0]=(short)f2bfbits(f0.x); v[1]=(short)f2bfbits(f0.y);
    v[2]=(short)f2bfbits(f0.z); v[3]=(short)f2bfbits(f0.w);
    v[4]=(short)f2bfbits(f1.x); v[5]=(short)f2bfbits(f1.y);
    v[6]=(short)f2bfbits(f1.z); v[7]=(short)f2bfbits(f1.w);
    return v;
  }
  static __device__ __forceinline__ float lds(const void* p, size_t i) {
    return ((const float*)p)[i];
  }
};

// ---- dtype detect: low u16 of each u32 word of x ----
__global__ void detect_k(const unsigned int* __restrict__ x, int* __restrict__ flag) {
  int tid = threadIdx.x;
  int cnt = 0;
  for (int i = tid; i < 256; i += 64) {
    float a = fabsf(bf2f((unsigned short)(x[i] & 0xffffu)));
    if (a > 1e-3f && a < 10.f) cnt++;
  }
  for (int off = 32; off >= 1; off >>= 1) cnt += __shfl_xor(cnt, off);
  if (tid == 0) *flag = (cnt >= 128) ? 1 : 0;
}

// ---- DMA MFMA GEMM (bf16 A and W): C = epi(A @ W^T + bias) ----
// Unpadded 64-B LDS rows; global_load_lds width-16 staging (m97 structure).
// Tile 128 x BN, BK=32, 4 waves, 16x16x32 bf16 MFMA. Modes as mfma_body.
template<int BN>
__device__ __forceinline__ void mfma_body_dma(
    const unsigned short* __restrict__ A, const unsigned short* __restrict__ W,
    const unsigned short* __restrict__ bias, void* __restrict__ Cv,
    int K, int lda, int ldb, int ldc, int mode, size_t csplit)
{
  extern __shared__ unsigned short smem[];
  unsigned short* As = smem;            // 128*32, unpadded
  unsigned short* Bs = smem + 128*32;   // BN*32, unpadded
  constexpr int MI = (BN == 128) ? 4 : 2;
  const int tid = threadIdx.x;
  const int m0 = blockIdx.x * 128;
  const int n0 = blockIdx.y * BN;
  const int kbase = blockIdx.z * K;
  const int lane = tid & 63;
  const int wv = tid >> 6;
  const int wm = (BN == 128) ? (wv >> 1) * 64 : wv * 32;
  const int wn = (BN == 128) ? (wv & 1) * 64 : 0;
  const int lr = lane & 15, lg = lane >> 4;
  const int drow = lane >> 2, dcol = (lane & 3) * 8;  // DMA: 4 lanes x 16 B per 64-B row

  f32x4 acc[MI][4];
  #pragma unroll
  for (int i = 0; i < MI; ++i)
    #pragma unroll
    for (int j = 0; j < 4; ++j) acc[i][j] = (f32x4){0.f, 0.f, 0.f, 0.f};

  for (int k0 = 0; k0 < K; k0 += 32) {
    __syncthreads();                     // prior iter's frag reads done
    #pragma unroll
    for (int q = 0; q < 2; ++q) {        // A: 8 chunks of 16 rows; 2 per wave
      int rb = (wv*2 + q) * 16;
      gload16(A + (size_t)(m0 + rb + drow)*lda + kbase + k0 + dcol, &As[rb*32]);
    }
    #pragma unroll
    for (int q = 0; q < BN/64; ++q) {    // B: BN/16 chunks; BN/64 per wave
      int rb = (wv*(BN/64) + q) * 16;
      gload16(W + (size_t)(n0 + rb + drow)*ldb + kbase + k0 + dcol, &Bs[rb*32]);
    }
    __syncthreads();                     // vmcnt(0) drain: DMA landed
    short8 af[MI], bfr[4];
    #pragma unroll
    for (int i = 0; i < MI; ++i)
      af[i] = *(const short8*)&As[(wm + i*16 + lr)*32 + lg*8];
    #pragma unroll
    for (int j = 0; j < 4; ++j)
      bfr[j] = *(const short8*)&Bs[(wn + j*16 + lr)*32 + lg*8];
    #pragma unroll
    for (int i = 0; i < MI; ++i)
      #pragma unroll
      for (int j = 0; j < 4; ++j)
        acc[i][j] = __builtin_amdgcn_mfma_f32_16x16x32_bf16(af[i], bfr[j], acc[i][j], 0, 0, 0);
  }

  size_t cz = (size_t)blockIdx.z * csplit;
  #pragma unroll
  for (int j = 0; j < 4; ++j) {
    int gn = n0 + wn + j*16 + lr;
    float bv = (mode == 1) ? bf2f(bias[gn]) : 0.f;
    #pragma unroll
    for (int i = 0; i < MI; ++i) {
      #pragma unroll
      for (int r = 0; r < 4; ++r) {
        int gm = m0 + wm + i*16 + lg*4 + r;
        float v = acc[i][j][r];
        if (mode == 1) {
          v += bv; v = v * sigmoidf_(v);
          ((unsigned short*)Cv)[cz + (size_t)gm*ldc + gn] = f2bfbits(v);
        } else if (mode == 3) {
          ((unsigned short*)Cv)[cz + (size_t)gm*ldc + gn] = f2bfbits(v);
        } else {
          ((float*)Cv)[cz + (size_t)gm*ldc + gn] = v;
        }
      }
    }
  }
}

// ---- fallback MFMA GEMM (padded LDS, manual staging) for fp32-input path ----
template<typename TA, typename TW, int BN>
__device__ __forceinline__ void mfma_body(
    const void* __restrict__ Av, const void* __restrict__ Wv,
    const void* __restrict__ biasv, void* __restrict__ Cv,
    int K, int lda, int ldb, int ldc, int mode, size_t csplit)
{
  extern __shared__ unsigned short smem[];
  unsigned short* As = smem;            // 128*40
  unsigned short* Bs = smem + 128*40;   // BN*40
  constexpr int MI = (BN == 128) ? 4 : 2;
  const int tid = threadIdx.x;
  const int m0 = blockIdx.x * 128;
  const int n0 = blockIdx.y * BN;
  const int kbase = blockIdx.z * K;
  const int lane = tid & 63;
  const int wv = tid >> 6;
  const int wm = (BN == 128) ? (wv >> 1) * 64 : wv * 32;
  const int wn = (BN == 128) ? (wv & 1) * 64 : 0;
  const int lr = lane & 15, lg = lane >> 4;

  f32x4 acc[MI][4];
  #pragma unroll
  for (int i = 0; i < MI; ++i)
    #pragma unroll
    for (int j = 0; j < 4; ++j) acc[i][j] = (f32x4){0.f, 0.f, 0.f, 0.f};

  for (int k0 = 0; k0 < K; k0 += 32) {
    short8 ra[2], rb[BN/64];
    #pragma unroll
    for (int r = 0; r < 2; ++r) {
      int chunk = tid + r*256;
      int row = chunk >> 2, sub = (chunk & 3) * 8;
      ra[r] = LD8<TA>::ld(Av, (size_t)(m0 + row)*lda + kbase + k0 + sub);
    }
    #pragma unroll
    for (int r = 0; r < BN/64; ++r) {
      int chunk = tid + r*256;
      int row = chunk >> 2, sub = (chunk & 3) * 8;
      rb[r] = LD8<TW>::ld(Wv, (size_t)(n0 + row)*ldb + kbase + k0 + sub);
    }
    __syncthreads();
    #pragma unroll
    for (int r = 0; r < 2; ++r) {
      int chunk = tid + r*256;
      int row = chunk >> 2, sub = (chunk & 3) * 8;
      *(short8*)&As[row*40 + sub] = ra[r];
    }
    #pragma unroll
    for (int r = 0; r < BN/64; ++r) {
      int chunk = tid + r*256;
      int row = chunk >> 2, sub = (chunk & 3) * 8;
      *(short8*)&Bs[row*40 + sub] = rb[r];
    }
    __syncthreads();
    short8 af[MI], bfr[4];
    #pragma unroll
    for (int i = 0; i < MI; ++i)
      af[i] = *(const short8*)&As[(wm + i*16 + lr)*40 + lg*8];
    #pragma unroll
    for (int j = 0; j < 4; ++j)
      bfr[j] = *(const short8*)&Bs[(wn + j*16 + lr)*40 + lg*8];
    #pragma unroll
    for (int i = 0; i < MI; ++i)
      #pragma unroll
      for (int j = 0; j < 4; ++j)
        acc[i][j] = __builtin_amdgcn_mfma_f32_16x16x32_bf16(af[i], bfr[j], acc[i][j], 0, 0, 0);
  }

  // C/D layout: col=lane&15, row=(lane>>4)*4+reg  [m89/m91 verified]
  size_t cz = (size_t)blockIdx.z * csplit;
  #pragma unroll
  for (int j = 0; j < 4; ++j) {
    int gn = n0 + wn + j*16 + lr;
    float bv = (mode == 1) ? LD8<TW>::lds(biasv, gn) : 0.f;
    #pragma unroll
    for (int i = 0; i < MI; ++i) {
      #pragma unroll
      for (int r = 0; r < 4; ++r) {
        int gm = m0 + wm + i*16 + lg*4 + r;
        float v = acc[i][j][r];
        if (mode == 1) {
          v += bv; v = v * sigmoidf_(v);
          ((unsigned short*)Cv)[cz + (size_t)gm*ldc + gn] = f2bfbits(v);
        } else if (mode == 3) {
          ((unsigned short*)Cv)[cz + (size_t)gm*ldc + gn] = f2bfbits(v);
        } else {
          ((float*)Cv)[cz + (size_t)gm*ldc + gn] = v;
        }
      }
    }
  }
}

template<int BN>
__global__ __launch_bounds__(256) void gemm_ain_k(const void* A, const void* W,
    const void* bias, void* C, int K, int lda, int ldb, int ldc, int mode,
    size_t csplit, const int* __restrict__ flag)
{
  if (*flag) mfma_body_dma<BN>((const unsigned short*)A, (const unsigned short*)W,
                               (const unsigned short*)bias, C, K, lda, ldb, ldc, mode, csplit);
  else       mfma_body<float, float, BN>(A, W, bias, C, K, lda, ldb, ldc, mode, csplit);
}
template<int BN>
__global__ __launch_bounds__(256) void gemm_a16_k(const void* A, const void* W,
    const void* bias, void* C, int K, int lda, int ldb, int ldc, int mode,
    size_t csplit, const int* __restrict__ flag)
{
  if (*flag) mfma_body_dma<BN>((const unsigned short*)A, (const unsigned short*)W,
                               (const unsigned short*)bias, C, K, lda, ldb, ldc, mode, csplit);
  else       mfma_body<unsigned short, float, BN>(A, W, bias, C, K, lda, ldb, ldc, mode, csplit);
}

// ---- delta GEMM: delta = softplus((xd0+xd1)[:, :32] @ W_dt^T + b_dt) -> bf16 ----
__global__ __launch_bounds__(256) void dt_gemm_k(
    const float* __restrict__ xd, const void* __restrict__ W_dt,
    const void* __restrict__ b_dt, unsigned short* __restrict__ delta,
    const int* __restrict__ flag)
{
  __shared__ unsigned short As[128*40];
  __shared__ unsigned short Bs[128*40];
  const int tid = threadIdx.x;
  const int m0 = blockIdx.x * 128;
  const int n0 = blockIdx.y * 128;
  const int fl = *flag;
  const int row = tid >> 1, half = (tid & 1) * 16;
  {  // stage A: (p0+p1)[m0+row][half..half+16) -> bf16
    size_t g = (size_t)(m0 + row)*64 + half;
    const float* p0 = xd + g;
    const float* p1 = xd + (size_t)ML*64 + g;
    short8 v0, v1;
    #pragma unroll
    for (int q = 0; q < 8; q += 4) {
      float4 a4 = *(const float4*)(p0 + q);
      float4 b4 = *(const float4*)(p1 + q);
      v0[q+0] = (short)f2bfbits(a4.x + b4.x);
      v0[q+1] = (short)f2bfbits(a4.y + b4.y);
      v0[q+2] = (short)f2bfbits(a4.z + b4.z);
      v0[q+3] = (short)f2bfbits(a4.w + b4.w);
    }
    #pragma unroll
    for (int q = 0; q < 8; q += 4) {
      float4 a4 = *(const float4*)(p0 + 8 + q);
      float4 b4 = *(const float4*)(p1 + 8 + q);
      v1[q+0] = (short)f2bfbits(a4.x + b4.x);
      v1[q+1] = (short)f2bfbits(a4.y + b4.y);
      v1[q+2] = (short)f2bfbits(a4.z + b4.z);
      v1[q+3] = (short)f2bfbits(a4.w + b4.w);
    }
    *(short8*)&As[row*40 + half] = v0;
    *(short8*)&As[row*40 + half + 8] = v1;
  }
  {  // stage B: W_dt[n0+row][half..half+16)
    *(short8*)&Bs[row*40 + half]     = fl ? LD8<unsigned short>::ld(W_dt, (size_t)(n0+row)*DTR + half)
                                          : LD8<float>::ld(W_dt, (size_t)(n0+row)*DTR + half);
    *(short8*)&Bs[row*40 + half + 8] = fl ? LD8<unsigned short>::ld(W_dt, (size_t)(n0+row)*DTR + half + 8)
                                          : LD8<float>::ld(W_dt, (size_t)(n0+row)*DTR + half + 8);
  }
  __syncthreads();
  const int lane = tid & 63;
  const int wv = tid >> 6;
  const int wm = (wv >> 1) * 64, wn = (wv & 1) * 64;
  const int lr = lane & 15, lg = lane >> 4;
  f32x4 acc[4][4];
  #pragma unroll
  for (int i = 0; i < 4; ++i)
    #pragma unroll
    for (int j = 0; j < 4; ++j) acc[i][j] = (f32x4){0.f, 0.f, 0.f, 0.f};
  short8 af[4], bfr[4];
  #pragma unroll
  for (int i = 0; i < 4; ++i)
    af[i] = *(const short8*)&As[(wm + i*16 + lr)*40 + lg*8];
  #pragma unroll
  for (int j = 0; j < 4; ++j)
    bfr[j] = *(const short8*)&Bs[(wn + j*16 + lr)*40 + lg*8];
  #pragma unroll
  for (int i = 0; i < 4; ++i)
    #pragma unroll
    for (int j = 0; j < 4; ++j)
      acc[i][j] = __builtin_amdgcn_mfma_f32_16x16x32_bf16(af[i], bfr[j], acc[i][j], 0, 0, 0);
  #pragma unroll
  for (int j = 0; j < 4; ++j) {
    int gn = n0 + wn + j*16 + lr;
    float bv = ldf(b_dt, gn, fl);
    #pragma unroll
    for (int i = 0; i < 4; ++i) {
      #pragma unroll
      for (int r = 0; r < 4; ++r) {
        int gm = m0 + wm + i*16 + lg*4 + r;
        float v = acc[i][j][r] + bv;
        v = (v > 20.f) ? v : __logf(1.f + __expf(v));
        delta[(size_t)gm*DI + gn] = f2bfbits(v);
      }
    }
  }
}

// ---- zlast v2: wave-per-row coalesced. grid (16 b, 16 jchunk of 64). ----
__global__ __launch_bounds__(256) void zlast2_k(const unsigned short* __restrict__ embed,
    const void* __restrict__ W_in, float* __restrict__ z_last, const int* __restrict__ flag)
{
  int b = blockIdx.x;
  int j0 = blockIdx.y * 64;
  int tid = threadIdx.x;
  __shared__ float e[DM];
  for (int i = tid; i < DM; i += 256)
    e[i] = bf2f(embed[(size_t)(b*L_ + L_-1)*DM + i]);
  __syncthreads();
  int fl = *flag;
  int wid = tid >> 6, lane = tid & 63;
  for (int jj = wid; jj < 64; jj += 4) {
    int j = j0 + jj;
    float p = 0.f;
    int k = lane * 8;                       // DM=512 = 64 lanes x 8
    if (fl) {
      const unsigned short* w = (const unsigned short*)W_in + (size_t)(DI + j)*DM + k;
      short8 v = *(const short8*)w;
      #pragma unroll
      for (int q = 0; q < 8; ++q) p += e[k+q]*bf2f((unsigned short)v[q]);
    } else {
      const float* w = (const float*)W_in + (size_t)(DI + j)*DM + k;
      float4 v0 = *(const float4*)w;
      float4 v1 = *(const float4*)(w + 4);
      p = e[k]*v0.x + e[k+1]*v0.y + e[k+2]*v0.z + e[k+3]*v0.w
        + e[k+4]*v1.x + e[k+5]*v1.y + e[k+6]*v1.z + e[k+7]*v1.w;
    }
    for (int off = 32; off >= 1; off >>= 1) p += __shfl_xor(p, off);
    if (lane == 0) z_last[b*DI + j] = p;
  }
}

// ---- causal depthwise conv + silu: xu bf16 -> u bf16 ----
__global__ __launch_bounds__(256) void conv_k(const unsigned short* __restrict__ xu,
    const void* __restrict__ conv_w, const void* __restrict__ conv_b,
    unsigned short* __restrict__ u, const int* __restrict__ flag)
{
  int bi = blockIdx.x;                    // 1024 blocks = b(16) x tc(16) x dchunk(4)
  int d  = (bi & 3)*256 + threadIdx.x;
  int tc = (bi >> 2) & 15;
  int b  = bi >> 6;
  int fl = *flag;
  float w0 = ldf(conv_w, (size_t)d*4 + 0, fl);
  float w1 = ldf(conv_w, (size_t)d*4 + 1, fl);
  float w2 = ldf(conv_w, (size_t)d*4 + 2, fl);
  float w3 = ldf(conv_w, (size_t)d*4 + 3, fl);
  float bias = ldf(conv_b, d, fl);
  int t0 = tc*64;
  const unsigned short* base = xu + (size_t)b*L_*DI + d;
  unsigned short* ubase = u + (size_t)b*L_*DI + d;
  float xm3 = (t0-3 >= 0) ? bf2f(base[(size_t)(t0-3)*DI]) : 0.f;
  float xm2 = (t0-2 >= 0) ? bf2f(base[(size_t)(t0-2)*DI]) : 0.f;
  float xm1 = (t0-1 >= 0) ? bf2f(base[(size_t)(t0-1)*DI]) : 0.f;
  for (int t = t0; t < t0+64; ++t) {
    float cur = bf2f(base[(size_t)t*DI]);
    float v = w0*xm3 + w1*xm2 + w2*xm1 + w3*cur + bias;
    ubase[(size_t)t*DI] = f2bfbits(v * sigmoidf_(v));
    xm3 = xm2; xm2 = xm1; xm1 = cur;
  }
}

// ---- scan v4: delta from memory (bf16); thread = 1 d, 16 n in registers. ----
__global__ __launch_bounds__(256) void scan4_k(
    const unsigned short* __restrict__ delta, const unsigned short* __restrict__ u,
    const float* __restrict__ xd, const void* __restrict__ A_log,
    float2* __restrict__ ps, const int* __restrict__ flag)
{
  const int b = blockIdx.x;
  const int d0 = blockIdx.y * 256;
  const int seg = blockIdx.z;
  const int t0 = seg * SEGT;
  const int tid = threadIdx.x;
  const int d = d0 + tid;
  const int fl = *flag;
  __shared__ float sB[SEGT*16];
  #pragma unroll
  for (int i = 0; i < SEGT*16/256; ++i) {
    int idx = tid + i*256;
    int row = idx >> 4, n = idx & 15;
    size_t g = (size_t)(b*L_ + t0 + row)*64 + 32 + n;
    sB[idx] = xd[g] + xd[(size_t)ML*64 + g];
  }
  float a[16], h[16];
  #pragma unroll
  for (int n = 0; n < 16; ++n) {
    a[n] = -__expf(ldf(A_log, (size_t)d*NST + n, fl));
    h[n] = 0.f;
  }
  float sdt = 0.f;
  const unsigned short* dp = delta + (size_t)(b*L_ + t0)*DI + d;
  const unsigned short* up = u + (size_t)(b*L_ + t0)*DI + d;
  __syncthreads();
  unsigned short nd = dp[0], nu = up[0];
  for (int t = 0; t < SEGT; ++t) {
    float dt = bf2f(nd), ut = bf2f(nu);
    if (t < SEGT-1) { nd = dp[(size_t)(t+1)*DI]; nu = up[(size_t)(t+1)*DI]; }
    float g = dt * ut;
    sdt += dt;
    const float* Br = &sB[t*16];
    #pragma unroll
    for (int n = 0; n < 16; ++n)
      h[n] = __expf(dt*a[n])*h[n] + g*Br[n];
  }
  #pragma unroll
  for (int n = 0; n < 16; ++n) {
    float P = __expf(a[n]*sdt);
    ps[(((size_t)seg*16 + b)*16 + n)*DI + d] = make_float2(P, h[n]);
  }
}

// ---- fold segments + C-dot -> 4 y-partials. grid (16 b, 4 dchunk, 4 nchunk). ----
__global__ __launch_bounds__(256) void combine4_k(const float2* __restrict__ ps,
    const float* __restrict__ xd, float* __restrict__ ypart)
{
  int b = blockIdx.x;
  int d = blockIdx.y * 256 + threadIdx.x;
  int n0 = blockIdx.z * 4;
  float h[4] = {0.f, 0.f, 0.f, 0.f};
  for (int s = 0; s < NSEG; ++s) {
    #pragma unroll
    for (int q = 0; q < 4; ++q) {
      float2 v = ps[(((size_t)s*16 + b)*16 + n0 + q)*DI + d];
      h[q] = v.x*h[q] + v.y;
    }
  }
  float y = 0.f;
  #pragma unroll
  for (int q = 0; q < 4; ++q) {
    size_t gl = (size_t)(b*L_ + L_-1)*64 + 48 + n0 + q;
    float cn = xd[gl] + xd[(size_t)ML*64 + gl];
    y += h[q]*cn;
  }
  ypart[((size_t)blockIdx.z*16 + b)*DI + d] = y;
}

// ---- mdot: m[b][row] = yz[b] . W_out[row]; wave-per-row coalesced. ----
__global__ __launch_bounds__(256) void mdot_k(const float* __restrict__ ypart,
    const unsigned short* __restrict__ u, const float* __restrict__ z_last,
    const void* __restrict__ Dskip, const void* __restrict__ W_out,
    float* __restrict__ m_out, const int* __restrict__ flag)
{
  int b = blockIdx.x;
  int r0 = blockIdx.y * 64;
  int tid = threadIdx.x;
  const int fl = *flag;
  __shared__ float yz[DI];
  for (int i = tid; i < DI; i += 256) {
    float ys = ypart[(size_t)b*DI + i] + ypart[(size_t)(16+b)*DI + i]
             + ypart[(size_t)(32+b)*DI + i] + ypart[(size_t)(48+b)*DI + i]
             + bf2f(u[(size_t)(b*L_ + L_-1)*DI + i]) * ldf(Dskip, i, fl);
    float z = z_last[b*DI + i];
    yz[i] = ys * (z * sigmoidf_(z));
  }
  __syncthreads();
  int wid = tid >> 6, lane = tid & 63;
  int k = lane * 8;                          // covers 512; second half at 512+k
  for (int rr = wid; rr < 64; rr += 4) {
    int row = r0 + rr;
    float p = 0.f;
    if (fl) {
      const unsigned short* w = (const unsigned short*)W_out + (size_t)row*DI;
      short8 v0 = *(const short8*)(w + k);
      short8 v1 = *(const short8*)(w + 512 + k);
      #pragma unroll
      for (int q = 0; q < 8; ++q)
        p += yz[k+q]*bf2f((unsigned short)v0[q]) + yz[512+k+q]*bf2f((unsigned short)v1[q]);
    } else {
      const float* w = (const float*)W_out + (size_t)row*DI;
      float4 a0 = *(const float4*)(w + k),      a1 = *(const float4*)(w + k + 4);
      float4 b0 = *(const float4*)(w + 512 + k), b1 = *(const float4*)(w + 512 + k + 4);
      p = yz[k]*a0.x + yz[k+1]*a0.y + yz[k+2]*a0.z + yz[k+3]*a0.w
        + yz[k+4]*a1.x + yz[k+5]*a1.y + yz[k+6]*a1.z + yz[k+7]*a1.w
        + yz[512+k]*b0.x + yz[512+k+1]*b0.y + yz[512+k+2]*b0.z + yz[512+k+3]*b0.w
        + yz[512+k+4]*b1.x + yz[512+k+5]*b1.y + yz[512+k+6]*b1.z + yz[512+k+7]*b1.w;
    }
    for (int off = 32; off >= 1; off >>= 1) p += __shfl_xor(p, off);
    if (lane == 0) m_out[b*DM + row] = p;
  }
}

// ---- head v2: layernorm(m) -> silu -> 17 head dots. 16 blocks x 512. ----
__global__ __launch_bounds__(512) void head2_k(const float* __restrict__ m_in,
    const void* __restrict__ W_critic, const void* __restrict__ b_critic,
    const void* __restrict__ W_amean, const void* __restrict__ b_amean,
    const void* __restrict__ W_astd, const void* __restrict__ b_astd,
    void* __restrict__ out, const int* __restrict__ flag)
{
  __shared__ float nb[DM];
  __shared__ float w1[8], w2[8];
  const int fl = *flag;
  int b = blockIdx.x;
  int tid = threadIdx.x;
  float m = m_in[b*DM + tid];
  float s1 = m, s2 = m*m;
  for (int off = 32; off >= 1; off >>= 1) { s1 += __shfl_xor(s1, off); s2 += __shfl_xor(s2, off); }
  int wid = tid >> 6, lane = tid & 63;
  if (lane == 0) { w1[wid] = s1; w2[wid] = s2; }
  __syncthreads();
  float t1 = 0.f, t2 = 0.f;
  for (int i = 0; i < 8; ++i) { t1 += w1[i]; t2 += w2[i]; }
  float mu  = t1 * (1.f/DM);
  float var = t2 * (1.f/DM) - mu*mu;
  float v = (m - mu) * rsqrtf(var + 1e-5f);
  nb[tid] = v * sigmoidf_(v);
  __syncthreads();
  for (int o = wid; o < 17; o += 8) {
    const void* w; size_t woff; float bias;
    if (o < 8)       { w = W_amean; woff = (size_t)o*DM;     bias = ldf(b_amean, o, fl); }
    else if (o < 16) { w = W_astd;  woff = (size_t)(o-8)*DM; bias = ldf(b_astd, o-8, fl); }
    else             { w = W_critic; woff = 0;               bias = ldf(b_critic, 0, fl); }
    float p = 0.f;
    for (int j = lane; j < DM; j += 64) p += nb[j] * ldf(w, woff + j, fl);
    for (int off = 32; off >= 1; off >>= 1) p += __shfl_xor(p, off);
    if (lane == 0) {
      float r = p + bias;
      int idx; float val;
      if (o < 8)       { idx = b*8 + o;           val = r; }
      else if (o < 16) { float ls = fminf(1.f, fmaxf(-1.f, r));
                         idx = 128 + b*8 + (o-8); val = expf(ls); }
      else             { idx = 256 + b;           val = r; }
      if (fl) ((bf16*)out)[idx] = __float2bfloat16(val);
      else    ((float*)out)[idx] = val;
    }
  }
}

extern "C" void kernel_launch(void* const* d_in, const int* in_sizes, int n_in,
                              void* d_out, int out_size, void* d_ws, size_t ws_size,
                              hipStream_t stream)
{
  const void* x        = d_in[0];
  const void* W_emb    = d_in[1];
  const void* b_emb    = d_in[2];
  const void* W_in     = d_in[3];
  const void* conv_w   = d_in[4];
  const void* conv_b   = d_in[5];
  const void* W_xproj  = d_in[6];
  const void* W_dt     = d_in[7];
  const void* b_dt     = d_in[8];
  const void* A_log    = d_in[9];
  const void* Dskip    = d_in[10];
  const void* W_out    = d_in[11];
  const void* W_critic = d_in[12];
  const void* b_critic = d_in[13];
  const void* W_amean  = d_in[14];
  const void* b_amean  = d_in[15];
  const void* W_astd   = d_in[16];
  const void* b_astd   = d_in[17];

  // workspace: embed 16 + xu 32 + u 32 + delta 32 + xdbl2 8 + ps 33.5 + small ~= 154 MB
  char* ws = (char*)d_ws;
  unsigned short* embed_bf = (unsigned short*)ws; ws += (size_t)ML*DM*2;
  unsigned short* xu_b  = (unsigned short*)ws; ws += (size_t)ML*DI*2;
  unsigned short* u_b   = (unsigned short*)ws; ws += (size_t)ML*DI*2;
  unsigned short* dlt_b = (unsigned short*)ws; ws += (size_t)ML*DI*2;
  float* xdbl2 = (float*)ws; ws += (size_t)2*ML*64*4;
  float2* psbuf = (float2*)ws; ws += (size_t)NSEG*B_*NST*DI*8;
  float* ypart = (float*)ws; ws += (size_t)4*B_*DI*4;
  float* zlast = (float*)ws; ws += (size_t)B_*DI*4;
  float* mbuf  = (float*)ws; ws += (size_t)B_*DM*4;
  int*   flag  = (int*)ws;   ws += 64;

  // 0. detect input dtype (bf16 vs fp32)
  detect_k<<<1, 64, 0, stream>>>((const unsigned int*)x, flag);
  // 1. embed = silu(x @ W_emb^T + b_emb) -> bf16   (M=16384, N=512, K=32)
  gemm_ain_k<128><<<dim3(ML/128, DM/128), 256, 256*40*2, stream>>>(
      x, W_emb, b_emb, embed_bf, 32, 32, 32, DM, 1, 0, flag);
  // 2. xu = embed @ W_in[:DI]^T -> bf16   (M=16384, N=1024, K=512; DMA staging)
  gemm_a16_k<128><<<dim3(ML/128, DI/128), 256, 256*40*2, stream>>>(
      embed_bf, W_in, nullptr, xu_b, DM, DM, DM, DI, 3, 0, flag);
  // 2b. z at last token only (wave-per-row coalesced)
  zlast2_k<<<dim3(16, 16), 256, 0, stream>>>(embed_bf, W_in, zlast, flag);
  // 3. u = silu(causal depthwise conv(xu)) -> bf16
  conv_k<<<1024, 256, 0, stream>>>(xu_b, conv_w, conv_b, u_b, flag);
  // 4. x_dbl = u @ W_xproj^T, split-K=2 -> two fp32 partials
  gemm_a16_k<64><<<dim3(ML/128, 1, 2), 256, 192*40*2, stream>>>(
      u_b, W_xproj, nullptr, xdbl2, 512, DI, DI, 64, 0, (size_t)ML*64, flag);
  // 5. delta = softplus(xdbl[:, :32] @ W_dt^T + b_dt) -> bf16  (MFMA, K=32)
  dt_gemm_k<<<dim3(ML/128, DI/128), 256, 0, stream>>>(
      xdbl2, W_dt, b_dt, dlt_b, flag);
  // 6. segmented scan (dt from memory) -> per-segment (P,S), coalesced layout
  scan4_k<<<dim3(B_, 4, NSEG), 256, 0, stream>>>(
      dlt_b, u_b, xdbl2, A_log, psbuf, flag);
  // 6b. fold segments + C-dot -> 4 y-partials
  combine4_k<<<dim3(B_, 4, 4), 256, 0, stream>>>(psbuf, xdbl2, ypart);
  // 7a. m = yz @ W_out^T (wave-per-row coalesced, 128 blocks)
  mdot_k<<<dim3(16, 8), 256, 0, stream>>>(ypart, u_b, zlast, Dskip, W_out, mbuf, flag);
  // 7b. layernorm + silu + 17 heads
  head2_k<<<16, 512, 0, stream>>>(mbuf, W_critic, b_critic,
                                  W_amean, b_amean, W_astd, b_astd, (void*)d_out, flag);
}